// Round 14
// baseline (414.407 us; speedup 1.0000x reference)
//
#include <hip/hip_runtime.h>
#include <hip/hip_bf16.h>
#include <hip/hip_fp16.h>

// Problem constants
#define B_   2048
#define NN   128    // NMAX
#define MM   64     // HN
#define HD_  128
#define IND  18
#define FD_  16

typedef unsigned int u32;
typedef _Float16 h2_t __attribute__((ext_vector_type(2)));
typedef __attribute__((ext_vector_type(8))) short bf16x8;
typedef __attribute__((ext_vector_type(4))) float f32x4;

__device__ __forceinline__ float fdot2f(u32 a, u32 b, float c) {
#if defined(__has_builtin)
#if __has_builtin(__builtin_amdgcn_fdot2)
  return __builtin_amdgcn_fdot2(__builtin_bit_cast(h2_t, a),
                                __builtin_bit_cast(h2_t, b), c, false);
#else
  h2_t x = __builtin_bit_cast(h2_t, a), y = __builtin_bit_cast(h2_t, b);
  return c + (float)x[0] * (float)y[0] + (float)x[1] * (float)y[1];
#endif
#else
  h2_t x = __builtin_bit_cast(h2_t, a), y = __builtin_bit_cast(h2_t, b);
  return c + (float)x[0] * (float)y[0] + (float)x[1] * (float)y[1];
#endif
}

__device__ __forceinline__ u32 pk2(float a, float b) {
#if defined(__has_builtin)
#if __has_builtin(__builtin_amdgcn_cvt_pkrtz)
  return __builtin_bit_cast(u32, __builtin_amdgcn_cvt_pkrtz(a, b));
#else
  __half ha = __float2half_rn(a), hb = __float2half_rn(b);
  return (u32)__half_as_ushort(ha) | ((u32)__half_as_ushort(hb) << 16);
#endif
#else
  __half ha = __float2half_rn(a), hb = __float2half_rn(b);
  return (u32)__half_as_ushort(ha) | ((u32)__half_as_ushort(hb) << 16);
#endif
}

__device__ __forceinline__ float rcpf_(float x) {
#if defined(__has_builtin)
#if __has_builtin(__builtin_amdgcn_rcpf)
  return __builtin_amdgcn_rcpf(x);
#else
  return 1.0f / x;
#endif
#else
  return 1.0f / x;
#endif
}

__device__ __forceinline__ float h_lo(u32 d) {
  return __half2float(__ushort_as_half((unsigned short)(d & 0xffffu)));
}
__device__ __forceinline__ float h_hi(u32 d) {
  return __half2float(__ushort_as_half((unsigned short)(d >> 16)));
}

__device__ __forceinline__ float bf2f(unsigned short u) {
  union { float f; u32 i; } z; z.i = ((u32)u) << 16; return z.f;
}
__device__ __forceinline__ unsigned short f2bf(float f) {
  union { float fv; u32 u; } z; z.fv = f;
  u32 lsb = (z.u >> 16) & 1u;
  return (unsigned short)((z.u + 0x7fffu + lsb) >> 16);
}
__device__ __forceinline__ u32 bfpk(float a, float b) {
  return (u32)f2bf(a) | ((u32)f2bf(b) << 16);
}
__device__ __forceinline__ bf16x8 ldfrag(const unsigned short* p) {
  return __builtin_bit_cast(bf16x8, *reinterpret_cast<const uint4*>(p));
}
__device__ __forceinline__ u32 comb2(u32 ps, u32 pf, float a, float na) {
  float r0 = a * bf2f((unsigned short)(ps & 0xffffu)) + na * bf2f((unsigned short)(pf & 0xffffu));
  float r1 = a * bf2f((unsigned short)(ps >> 16)) + na * bf2f((unsigned short)(pf >> 16));
  return (u32)f2bf(r0) | ((u32)f2bf(r1) << 16);
}

// ---------------------------------------------------------------------------
// FUSED kernel (R14): one block per batch, 512 threads (8 waves), 2 blocks/CU
// (16 waves/CU = 4/SIMD, 2x R13's occupancy). Same LDS plan as R13 (70 KB).
//  Phase A: wave w: stream sw=w&1, quarter qr=w>>2? no: qr=w>>1 (0..3),
//    slices mt = 2qr, 2qr+1. actw scratch: waves 0-3 in Z1T, waves 4-7 in adjb.
//  Phase B: waves 0,1 = full 1-wave R7 Sinkhorn per stream, P in place over
//    Ksh[w]; waves 2-7 stage adj half 0.
//  Phase C: M1/M2 split by (rowgroup g=w>>1, j-half jh=w&1), 8 MFMAs/wave;
//    M3 + LN2 contributions from jh==0 waves.
// ---------------------------------------------------------------------------
#define AP 136   // bf16 row pitch (272 B)

__launch_bounds__(512, 4)
__global__ void fused_kernel(const float* __restrict__ x,
                             const float* __restrict__ adj,
                             const float* __restrict__ w1,
                             const float* __restrict__ w2,
                             const float* __restrict__ alpha_p,
                             const float* __restrict__ bin_score,
                             const float* __restrict__ fc2w, const float* __restrict__ fc2b,
                             const float* __restrict__ fc3w, const float* __restrict__ fc3b,
                             const float* __restrict__ ln1g, const float* __restrict__ ln1b,
                             const float* __restrict__ ln2g, const float* __restrict__ ln2b,
                             unsigned short* __restrict__ lnadj,
                             unsigned short* __restrict__ lnfeats)
{
  __shared__ __align__(16) u32 Ksh[2][64 * 68];            // 34816 B (K then P)
  __shared__ __align__(16) u32 vhs[2][64];
  __shared__ __align__(16) u32 uhs[2][32];
  __shared__ __align__(16) unsigned short adjb[64 * AP];   // 17408 B
  __shared__ __align__(16) unsigned short Z1T[64 * AP];    // 17408 B
  __shared__ float red[32];

  const int tid = threadIdx.x;
  const int w8 = tid >> 6;          // wave 0..7
  const int lane = tid & 63;
  const int l15 = lane & 15, q = lane >> 4;
  const int b = blockIdx.x;

  // ======================= Phase A: scores -> K ==========================
  {
    const int sw = w8 & 1;            // stream
    const int qr = w8 >> 1;           // quarter 0..3
    const float* wm = sw ? w2 : w1;
    const float* fw = sw ? fc3w : fc2w;
    const float* fb = sw ? fc3b : fc2b;
    unsigned short* Kshh = reinterpret_cast<unsigned short*>(Ksh[sw]);
    unsigned short* actw = (w8 < 4) ? (Z1T + (size_t)w8 * (16 * AP))
                                    : (adjb + (size_t)(w8 - 4) * (16 * AP));

    uint4 wA[4][4];
    #pragma unroll
    for (int at = 0; at < 4; ++at) {
      const float* wrow = wm + (size_t)(16 * at + l15) * 128;
      #pragma unroll
      for (int kt = 0; kt < 4; ++kt) {
        float4 va = *reinterpret_cast<const float4*>(wrow + 32 * kt + 8 * q);
        float4 vb = *reinterpret_cast<const float4*>(wrow + 32 * kt + 8 * q + 4);
        wA[at][kt] = make_uint4(bfpk(va.x, va.y), bfpk(va.z, va.w),
                                bfpk(vb.x, vb.y), bfpk(vb.z, vb.w));
      }
    }
    uint4 fcwB[8];
    #pragma unroll
    for (int nt = 0; nt < 8; ++nt) {
      const int ch = 16 * nt + l15;
      uint4 o = make_uint4(0u, 0u, 0u, 0u);
      if (sw) {
        if (q < 2) {
          const float* fr = fw + (size_t)ch * 16 + 8 * q;
          float4 va = *reinterpret_cast<const float4*>(fr);
          float4 vb = *reinterpret_cast<const float4*>(fr + 4);
          o = make_uint4(bfpk(va.x, va.y), bfpk(va.z, va.w),
                         bfpk(vb.x, vb.y), bfpk(vb.z, vb.w));
        }
      } else {
        if (q == 0) o.x = bfpk(fw[ch * 2], fw[ch * 2 + 1]);
      }
      fcwB[nt] = o;
    }
    float bb[8];
    #pragma unroll
    for (int nt = 0; nt < 8; ++nt) bb[nt] = fb[16 * nt + l15];

    uint4 xa[2];
    #pragma unroll
    for (int mi = 0; mi < 2; ++mi) {
      const int node = 16 * (2 * qr + mi) + l15;
      const float* xp = x + ((size_t)b * NN + node) * IND + (sw ? 2 : 0);
      uint4 o = make_uint4(0u, 0u, 0u, 0u);
      if (sw) {
        if (q < 2) {
          float2 p0 = *reinterpret_cast<const float2*>(xp + 8 * q);
          float2 p1 = *reinterpret_cast<const float2*>(xp + 8 * q + 2);
          float2 p2 = *reinterpret_cast<const float2*>(xp + 8 * q + 4);
          float2 p3 = *reinterpret_cast<const float2*>(xp + 8 * q + 6);
          o = make_uint4(bfpk(p0.x, p0.y), bfpk(p1.x, p1.y),
                         bfpk(p2.x, p2.y), bfpk(p3.x, p3.y));
        }
      } else {
        if (q == 0) {
          float2 p0 = *reinterpret_cast<const float2*>(xp);
          o.x = bfpk(p0.x, p0.y);
        }
      }
      xa[mi] = o;
    }

    #pragma unroll
    for (int mi = 0; mi < 2; ++mi) {
      const int mt = 2 * qr + mi;
      f32x4 acc[8];
      #pragma unroll
      for (int nt = 0; nt < 8; ++nt)
        acc[nt] = __builtin_amdgcn_mfma_f32_16x16x32_bf16(
            __builtin_bit_cast(bf16x8, xa[mi]), __builtin_bit_cast(bf16x8, fcwB[nt]),
            f32x4{0.f, 0.f, 0.f, 0.f}, 0, 0, 0);
      #pragma unroll
      for (int nt = 0; nt < 8; ++nt) {
        #pragma unroll
        for (int r = 0; r < 4; ++r) {
          float v = fmaxf(acc[nt][r] + bb[nt], 0.0f);
          actw[(4 * q + r) * AP + 16 * nt + l15] = f2bf(v);
        }
      }
      uint4 sB[4];
      #pragma unroll
      for (int kt = 0; kt < 4; ++kt)
        sB[kt] = *reinterpret_cast<const uint4*>(&actw[l15 * AP + 32 * kt + 8 * q]);
      #pragma unroll
      for (int at = 0; at < 4; ++at) {
        f32x4 sa = f32x4{0.f, 0.f, 0.f, 0.f};
        #pragma unroll
        for (int kt = 0; kt < 4; ++kt)
          sa = __builtin_amdgcn_mfma_f32_16x16x32_bf16(
              __builtin_bit_cast(bf16x8, wA[at][kt]), __builtin_bit_cast(bf16x8, sB[kt]),
              sa, 0, 0, 0);
        #pragma unroll
        for (int r = 0; r < 4; ++r) {
          float kv = fminf(__expf(fmaxf(sa[r], 0.0f)), 60000.0f);
          Kshh[(16 * at + 4 * q + r) * AP + 16 * mt + l15] =
              __half_as_ushort(__float2half_rn(kv));
        }
      }
    }
  }
  __syncthreads();   // Ksh[0..1] complete; Z1T/adjb scratch dead

  const float ebs = __expf(bin_score[0]);

  // ======= Phase B: Sinkhorn (waves 0,1) | adj h0 staging (waves 2-7) ====
  if (w8 < 2) {
    const int l = lane;
    u32* Ks = Ksh[w8];
    u32 kr[64];
    #pragma unroll
    for (int t = 0; t < 16; ++t) {
      uint4 kv = *reinterpret_cast<const uint4*>(Ks + l * 68 + 4 * t);
      kr[4 * t + 0] = kv.x; kr[4 * t + 1] = kv.y;
      kr[4 * t + 2] = kv.z; kr[4 * t + 3] = kv.w;
    }
    u32 kta[32], ktb[32];
    #pragma unroll
    for (int j = 0; j < 32; ++j) {
      u32 d0 = Ks[(2 * j) * 68 + l];
      u32 d1 = Ks[(2 * j + 1) * 68 + l];
      kta[j] = (d0 & 0xffffu) | (d1 << 16);
      ktb[j] = (d0 >> 16) | (d1 & 0xffff0000u);
    }

    u32* vh = vhs[w8];
    u32* uh = uhs[w8];
    vh[l] = 0x3C003C00u;
    float v128 = 1.0f, sum_v = 129.0f;
    float u_old = 0.0f, vo0 = 1.0f, vo1 = 1.0f;
    float ur = 0.0f;
    const float TOL = 1.5e-3f;

    for (int it = 0; it < 100; ++it) {
      const float u64v = 128.0f * rcpf_(ebs * sum_v);
      float a0 = ebs * v128, a1 = 0.f, a2 = 0.f, a3 = 0.f;
      const uint4* vh4 = reinterpret_cast<const uint4*>(vh);
      #pragma unroll
      for (int t = 0; t < 16; ++t) {
        uint4 vvv = vh4[t];
        a0 = fdot2f(kr[4 * t + 0], vvv.x, a0);
        a1 = fdot2f(kr[4 * t + 1], vvv.y, a1);
        a2 = fdot2f(kr[4 * t + 2], vvv.z, a2);
        a3 = fdot2f(kr[4 * t + 3], vvv.w, a3);
      }
      float urn = rcpf_((a0 + a1) + (a2 + a3));
      float m1 = fabsf(urn - u_old) - TOL * urn;
      u_old = urn; ur = urn;
      float su = urn;
      su += __shfl_xor(su, 1);  su += __shfl_xor(su, 2);
      su += __shfl_xor(su, 4);  su += __shfl_xor(su, 8);
      su += __shfl_xor(su, 16); su += __shfl_xor(su, 32);
      const float sum_u = su + u64v;
      const float v128n = 64.0f * rcpf_(ebs * sum_u);
      float upr = __shfl_xor(urn, 1);
      if (!(l & 1)) uh[l >> 1] = pk2(urn, upr);
      float c0a = ebs * u64v, c0b = 0.f, c1a = ebs * u64v, c1b = 0.f;
      const uint4* uh4 = reinterpret_cast<const uint4*>(uh);
      #pragma unroll
      for (int t = 0; t < 8; ++t) {
        uint4 uu = uh4[t];
        c0a = fdot2f(kta[4 * t + 0], uu.x, c0a);
        c0b = fdot2f(kta[4 * t + 1], uu.y, c0b);
        c0a = fdot2f(kta[4 * t + 2], uu.z, c0a);
        c0b = fdot2f(kta[4 * t + 3], uu.w, c0b);
        c1a = fdot2f(ktb[4 * t + 0], uu.x, c1a);
        c1b = fdot2f(ktb[4 * t + 1], uu.y, c1b);
        c1a = fdot2f(ktb[4 * t + 2], uu.z, c1a);
        c1b = fdot2f(ktb[4 * t + 3], uu.w, c1b);
      }
      float v0n = rcpf_(c0a + c0b);
      float v1n = rcpf_(c1a + c1b);
      float m2 = fabsf(v0n - vo0) - TOL * v0n;
      float m3 = fabsf(v1n - vo1) - TOL * v1n;
      vo0 = v0n; vo1 = v1n;
      vh[l] = pk2(v0n, v1n);
      float sv = v0n + v1n;
      sv += __shfl_xor(sv, 1);  sv += __shfl_xor(sv, 2);
      sv += __shfl_xor(sv, 4);  sv += __shfl_xor(sv, 8);
      sv += __shfl_xor(sv, 16); sv += __shfl_xor(sv, 32);
      sum_v = sv + v128n;
      v128 = v128n;
      float mcond = fmaxf(m1, fmaxf(m2, m3));
      if (__all(mcond <= 0.0f)) break;
    }

    // P = K*u*v bf16 in place over Ksh[w8]
    {
      const uint4* vh4 = reinterpret_cast<const uint4*>(vh);
      #pragma unroll
      for (int t = 0; t < 16; ++t) {
        uint4 vvv = vh4[t];
        u32 o0 = bfpk(h_lo(kr[4 * t + 0]) * ur * h_lo(vvv.x),
                      h_hi(kr[4 * t + 0]) * ur * h_hi(vvv.x));
        u32 o1 = bfpk(h_lo(kr[4 * t + 1]) * ur * h_lo(vvv.y),
                      h_hi(kr[4 * t + 1]) * ur * h_hi(vvv.y));
        u32 o2 = bfpk(h_lo(kr[4 * t + 2]) * ur * h_lo(vvv.z),
                      h_hi(kr[4 * t + 2]) * ur * h_hi(vvv.z));
        u32 o3 = bfpk(h_lo(kr[4 * t + 3]) * ur * h_lo(vvv.w),
                      h_hi(kr[4 * t + 3]) * ur * h_hi(vvv.w));
        *reinterpret_cast<uint4*>(&Ks[l * 68 + 4 * t]) = make_uint4(o0, o1, o2, o3);
      }
    }
  } else {
    // stage adj rows 0..63 -> adjb (384 threads)
    const float4* src = reinterpret_cast<const float4*>(adj + (size_t)b * (NN * NN));
    for (int i = tid - 128; i < 64 * 32; i += 384) {
      int row = i >> 5, c4 = i & 31;
      float4 v = src[i];
      u32 w0 = (u32)f2bf(v.x) | ((u32)f2bf(v.y) << 16);
      u32 w1 = (u32)f2bf(v.z) | ((u32)f2bf(v.w) << 16);
      *reinterpret_cast<uint2*>(&adjb[row * AP + c4 * 4]) = make_uint2(w0, w1);
    }
  }
  __syncthreads();   // P0,P1 in Ksh; adjb h0 staged

  // ======================= Phase C: align ================================
  const int g = w8 >> 1;     // rowgroup 0..3
  const int jh = w8 & 1;     // j-half
  const float aa = 1.0f / (1.0f + __expf(-alpha_p[0]));
  const float na = 1.0f - aa;
  for (int i = tid; i < 4096; i += 512) {
    int row = i >> 6, cd = i & 63;
    Ksh[0][row * 68 + cd] = comb2(Ksh[0][row * 68 + cd], Ksh[1][row * 68 + cd], aa, na);
  }
  __syncthreads();
  const unsigned short* Pc = reinterpret_cast<const unsigned short*>(Ksh[0]);

  // M1 half 0
  {
    f32x4 acch[2];
    acch[0] = f32x4{0.f, 0.f, 0.f, 0.f};
    acch[1] = f32x4{0.f, 0.f, 0.f, 0.f};
    #pragma unroll
    for (int kt = 0; kt < 4; ++kt) {
      const int d0 = 32 * kt + 8 * q;
      bf16x8 af = ldfrag(&adjb[(16 * g + l15) * AP + d0]);
      #pragma unroll
      for (int jj = 0; jj < 2; ++jj) {
        bf16x8 bf = ldfrag(&Pc[(16 * (2 * jh + jj) + l15) * AP + d0]);
        acch[jj] = __builtin_amdgcn_mfma_f32_16x16x32_bf16(af, bf, acch[jj], 0, 0, 0);
      }
    }
    __syncthreads();   // Z1T scratch dead before writes
    #pragma unroll
    for (int jj = 0; jj < 2; ++jj) {
      const int k = 16 * (2 * jh + jj) + l15;
      const int nbase = 16 * g + 4 * q;
      u32 w0 = (u32)f2bf(acch[jj][0]) | ((u32)f2bf(acch[jj][1]) << 16);
      u32 w1 = (u32)f2bf(acch[jj][2]) | ((u32)f2bf(acch[jj][3]) << 16);
      *reinterpret_cast<uint2*>(&Z1T[k * AP + nbase]) = make_uint2(w0, w1);
    }
  }
  __syncthreads();   // adjb h0 reads done

  // stage adj rows 64..127
  {
    const float4* src = reinterpret_cast<const float4*>(
        adj + (size_t)b * (NN * NN) + (size_t)64 * NN);
    for (int i = tid; i < 64 * 32; i += 512) {
      int row = i >> 5, c4 = i & 31;
      float4 v = src[i];
      u32 w0 = (u32)f2bf(v.x) | ((u32)f2bf(v.y) << 16);
      u32 w1 = (u32)f2bf(v.z) | ((u32)f2bf(v.w) << 16);
      *reinterpret_cast<uint2*>(&adjb[row * AP + c4 * 4]) = make_uint2(w0, w1);
    }
  }
  __syncthreads();

  // M1 half 1
  {
    f32x4 acch[2];
    acch[0] = f32x4{0.f, 0.f, 0.f, 0.f};
    acch[1] = f32x4{0.f, 0.f, 0.f, 0.f};
    #pragma unroll
    for (int kt = 0; kt < 4; ++kt) {
      const int d0 = 32 * kt + 8 * q;
      bf16x8 af = ldfrag(&adjb[(16 * g + l15) * AP + d0]);
      #pragma unroll
      for (int jj = 0; jj < 2; ++jj) {
        bf16x8 bf = ldfrag(&Pc[(16 * (2 * jh + jj) + l15) * AP + d0]);
        acch[jj] = __builtin_amdgcn_mfma_f32_16x16x32_bf16(af, bf, acch[jj], 0, 0, 0);
      }
    }
    #pragma unroll
    for (int jj = 0; jj < 2; ++jj) {
      const int k = 16 * (2 * jh + jj) + l15;
      const int nbase = 64 + 16 * g + 4 * q;
      u32 w0 = (u32)f2bf(acch[jj][0]) | ((u32)f2bf(acch[jj][1]) << 16);
      u32 w1 = (u32)f2bf(acch[jj][2]) | ((u32)f2bf(acch[jj][3]) << 16);
      *reinterpret_cast<uint2*>(&Z1T[k * AP + nbase]) = make_uint2(w0, w1);
    }
  }
  __syncthreads();   // Z1T complete; adjb free

  // stage xfT into adjb tail
  unsigned short* xfT = adjb + 48 * AP;
  for (int i = tid; i < 2048; i += 512) {
    int n = i & 127, f = i >> 7;
    xfT[f * AP + n] = f2bf(x[((size_t)b * NN + n) * IND + 2 + f]);
  }
  __syncthreads();

  // M2 (j-half) + M3 (jh==0 only)
  f32x4 acc2[2];
  acc2[0] = f32x4{0.f, 0.f, 0.f, 0.f};
  acc2[1] = f32x4{0.f, 0.f, 0.f, 0.f};
  f32x4 acc3 = f32x4{0.f, 0.f, 0.f, 0.f};
  #pragma unroll
  for (int nt = 0; nt < 4; ++nt) {
    const int n0 = 32 * nt + 8 * q;
    bf16x8 af = ldfrag(&Pc[(16 * g + l15) * AP + n0]);
    #pragma unroll
    for (int jj = 0; jj < 2; ++jj) {
      bf16x8 bv = ldfrag(&Z1T[(16 * (2 * jh + jj) + l15) * AP + n0]);
      acc2[jj] = __builtin_amdgcn_mfma_f32_16x16x32_bf16(af, bv, acc2[jj], 0, 0, 0);
    }
    if (jh == 0) {
      bf16x8 bx = ldfrag(&xfT[l15 * AP + n0]);
      acc3 = __builtin_amdgcn_mfma_f32_16x16x32_bf16(af, bx, acc3, 0, 0, 0);
    }
  }

  // LN reductions (8 waves)
  {
    float s1 = 0.f, q1 = 0.f, s2 = 0.f, q2 = 0.f;
    #pragma unroll
    for (int jj = 0; jj < 2; ++jj)
      #pragma unroll
      for (int r = 0; r < 4; ++r) { float v = acc2[jj][r]; s1 += v; q1 += v * v; }
    if (jh == 0) {
      #pragma unroll
      for (int r = 0; r < 4; ++r) { float v = acc3[r]; s2 += v; q2 += v * v; }
    }
    #pragma unroll
    for (int off = 1; off < 64; off <<= 1) {
      s1 += __shfl_xor(s1, off); q1 += __shfl_xor(q1, off);
      s2 += __shfl_xor(s2, off); q2 += __shfl_xor(q2, off);
    }
    if (lane == 0) { red[w8] = s1; red[8 + w8] = q1; red[16 + w8] = s2; red[24 + w8] = q2; }
  }
  __syncthreads();
  float S1 = 0.f, Q1 = 0.f, S2 = 0.f, Q2 = 0.f;
  #pragma unroll
  for (int i = 0; i < 8; ++i) {
    S1 += red[i]; Q1 += red[8 + i]; S2 += red[16 + i]; Q2 += red[24 + i];
  }
  const float mean1 = S1 * (1.0f / 4096.0f);
  const float rstd1 = rsqrtf(Q1 * (1.0f / 4096.0f) - mean1 * mean1 + 1e-5f);
  const float mean2 = S2 * (1.0f / 1024.0f);
  const float rstd2 = rsqrtf(Q2 * (1.0f / 1024.0f) - mean2 * mean2 + 1e-5f);

  // normalize + bounce (ob1 = adjb head; ob2 = Z1T head — after barrier)
  __syncthreads();
  unsigned short* ob1 = adjb;
  unsigned short* ob2 = Z1T;
  #pragma unroll
  for (int jj = 0; jj < 2; ++jj) {
    const int k = 16 * (2 * jh + jj) + l15;
    #pragma unroll
    for (int r = 0; r < 4; ++r) {
      const int m = 16 * g + 4 * q + r;
      const int pos = m * 64 + k;
      float vv2 = (acc2[jj][r] - mean1) * rstd1 * ln1g[pos] + ln1b[pos];
      ob1[pos] = f2bf(vv2);
    }
  }
  if (jh == 0) {
    const int f = l15;
    #pragma unroll
    for (int r = 0; r < 4; ++r) {
      const int m = 16 * g + 4 * q + r;
      const int pos = m * 16 + f;
      float vv2 = (acc3[r] - mean2) * rstd2 * ln2g[pos] + ln2b[pos];
      ob2[pos] = f2bf(vv2);
    }
  }
  __syncthreads();
  {
    const uint4* sp = reinterpret_cast<const uint4*>(ob1);
    uint4* dp = reinterpret_cast<uint4*>(lnadj + (size_t)b * 4096);
    for (int i = tid; i < 512; i += 512) dp[i] = sp[i];
    if (tid < 128)
      reinterpret_cast<uint4*>(lnfeats + (size_t)b * 1024)[tid] =
          reinterpret_cast<const uint4*>(ob2)[tid];
  }
}

// ---------------------------------------------------------------------------
// Kernel C (MFMA): unchanged.
// ---------------------------------------------------------------------------
#define GP 72
__launch_bounds__(256, 2)
__global__ void gemm_mfma_kernel(const unsigned short* __restrict__ A,
                                 const float* __restrict__ W,
                                 const float* __restrict__ bias,
                                 float* __restrict__ C,
                                 int K, int ldc, int coff)
{
  __shared__ __align__(16) unsigned short At[64 * GP];
  __shared__ __align__(16) unsigned short Wt[64 * GP];
  const int tid = threadIdx.x;
  const int m0 = blockIdx.x * 64;
  const int n0 = blockIdx.y * 64;
  const int w = tid >> 6, lane = tid & 63;
  const int l15 = lane & 15, q = lane >> 4;
  const int srow = tid >> 2, sko = (tid & 3) * 16;

  f32x4 acc[4];
  #pragma unroll
  for (int j = 0; j < 4; ++j) acc[j] = f32x4{0.f, 0.f, 0.f, 0.f};

  for (int kc = 0; kc < K; kc += 64) {
    __syncthreads();
    {
      const unsigned short* ap = &A[(size_t)(m0 + srow) * K + kc + sko];
      *reinterpret_cast<uint4*>(&At[srow * GP + sko]) =
          *reinterpret_cast<const uint4*>(ap);
      *reinterpret_cast<uint4*>(&At[srow * GP + sko + 8]) =
          *reinterpret_cast<const uint4*>(ap + 8);
      const float* wp = &W[(size_t)(n0 + srow) * K + kc + sko];
      const float4 v0 = reinterpret_cast<const float4*>(wp)[0];
      const float4 v1 = reinterpret_cast<const float4*>(wp)[1];
      const float4 v2 = reinterpret_cast<const float4*>(wp)[2];
      const float4 v3 = reinterpret_cast<const float4*>(wp)[3];
      uint4 o0, o1;
      o0.x = (u32)f2bf(v0.x) | ((u32)f2bf(v0.y) << 16);
      o0.y = (u32)f2bf(v0.z) | ((u32)f2bf(v0.w) << 16);
      o0.z = (u32)f2bf(v1.x) | ((u32)f2bf(v1.y) << 16);
      o0.w = (u32)f2bf(v1.z) | ((u32)f2bf(v1.w) << 16);
      o1.x = (u32)f2bf(v2.x) | ((u32)f2bf(v2.y) << 16);
      o1.y = (u32)f2bf(v2.z) | ((u32)f2bf(v2.w) << 16);
      o1.z = (u32)f2bf(v3.x) | ((u32)f2bf(v3.y) << 16);
      o1.w = (u32)f2bf(v3.z) | ((u32)f2bf(v3.w) << 16);
      *reinterpret_cast<uint4*>(&Wt[srow * GP + sko]) = o0;
      *reinterpret_cast<uint4*>(&Wt[srow * GP + sko + 8]) = o1;
    }
    __syncthreads();
    #pragma unroll
    for (int s = 0; s < 2; ++s) {
      bf16x8 af = ldfrag(&At[(16 * w + l15) * GP + 32 * s + 8 * q]);
      #pragma unroll
      for (int j = 0; j < 4; ++j) {
        bf16x8 bf = ldfrag(&Wt[(16 * j + l15) * GP + 32 * s + 8 * q]);
        acc[j] = __builtin_amdgcn_mfma_f32_16x16x32_bf16(af, bf, acc[j], 0, 0, 0);
      }
    }
  }
  #pragma unroll
  for (int j = 0; j < 4; ++j) {
    const int col = n0 + 16 * j + l15;
    const float bb = bias[col];
    #pragma unroll
    for (int r = 0; r < 4; ++r) {
      const int m = m0 + 16 * w + 4 * q + r;
      C[(size_t)m * ldc + coff + col] = fmaxf(acc[j][r] + bb, 0.0f);
    }
  }
}

// ---------------------------------------------------------------------------
// Kernel D: unchanged (8 rows/block).
// ---------------------------------------------------------------------------
__launch_bounds__(256)
__global__ void head_kernel(const float* __restrict__ h45,
                            const float* __restrict__ wT6,   // [512][64]
                            const float* __restrict__ b6,
                            const float* __restrict__ w7,    // [10][64]
                            const float* __restrict__ b7,
                            float* __restrict__ out)
{
  __shared__ float row[8][512];
  __shared__ float h6[8][64];
  __shared__ float zb[8][12];
  const int tid = threadIdx.x;
  const int r0 = blockIdx.x * 8;
  for (int i = tid; i < 8 * 128; i += 256) {
    int r = i >> 7, c4 = i & 127;
    *reinterpret_cast<float4*>(&row[r][c4 * 4]) =
        reinterpret_cast<const float4*>(h45 + (size_t)(r0 + r) * 512)[c4];
  }
  __syncthreads();
  const int o = tid & 63, rg = tid >> 6;
  float a0 = b6[o], a1 = a0;
  #pragma unroll 8
  for (int k = 0; k < 512; ++k) {
    float wv = wT6[k * 64 + o];
    a0 += row[rg][k] * wv;
    a1 += row[rg + 4][k] * wv;
  }
  h6[rg][o] = fmaxf(a0, 0.0f);
  h6[rg + 4][o] = fmaxf(a1, 0.0f);
  __syncthreads();
  if (tid < 80) {
    int r = tid / 10, c = tid - r * 10;
    float z = b7[c];
    #pragma unroll
    for (int k = 0; k < 64; ++k) z += h6[r][k] * w7[c * 64 + k];
    zb[r][c] = z;
  }
  __syncthreads();
  if (tid < 80) {
    int r = tid / 10, c = tid - r * 10;
    float mx = zb[r][0];
    #pragma unroll
    for (int j = 1; j < 10; ++j) mx = fmaxf(mx, zb[r][j]);
    float se = 0.f;
    #pragma unroll
    for (int j = 0; j < 10; ++j) se += __expf(zb[r][j] - mx);
    out[(size_t)(r0 + r) * 10 + c] = zb[r][c] - mx - __logf(se);
  }
}

__global__ void transpose_kernel(const float* __restrict__ in, float* __restrict__ outp,
                                 int R, int Cc)
{
  int idx = blockIdx.x * blockDim.x + threadIdx.x;
  int total = R * Cc;
  for (; idx < total; idx += gridDim.x * blockDim.x) {
    int rr = idx / Cc, cc = idx - rr * Cc;
    outp[cc * R + rr] = in[idx];
  }
}

// ---------------------------------------------------------------------------
extern "C" void kernel_launch(void* const* d_in, const int* in_sizes, int n_in,
                              void* d_out, int out_size, void* d_ws, size_t ws_size,
                              hipStream_t stream)
{
  (void)in_sizes; (void)n_in; (void)out_size; (void)ws_size;
  const float* x    = (const float*)d_in[0];
  const float* adj  = (const float*)d_in[1];
  const float* w1   = (const float*)d_in[2];
  const float* w2   = (const float*)d_in[3];
  const float* alpha = (const float*)d_in[4];
  const float* bin_score = (const float*)d_in[5];
  const float* fc2w = (const float*)d_in[6];
  const float* fc2b = (const float*)d_in[7];
  const float* fc3w = (const float*)d_in[8];
  const float* fc3b = (const float*)d_in[9];
  const float* ln1g = (const float*)d_in[10];
  const float* ln1b = (const float*)d_in[11];
  const float* fc4w = (const float*)d_in[12];
  const float* fc4b = (const float*)d_in[13];
  const float* ln2g = (const float*)d_in[14];
  const float* ln2b = (const float*)d_in[15];
  const float* fc5w = (const float*)d_in[16];
  const float* fc5b = (const float*)d_in[17];
  const float* fc6w = (const float*)d_in[18];
  const float* fc6b = (const float*)d_in[19];
  const float* fc7w = (const float*)d_in[20];
  const float* fc7b = (const float*)d_in[21];
  float* out = (float*)d_out;

  char* ws = (char*)d_ws;
  size_t off = 0;
  unsigned short* lnadj = (unsigned short*)(ws + off);  off += (size_t)2048 * 4096 * 2;
  unsigned short* lnfeats = (unsigned short*)(ws + off); off += (size_t)2048 * 1024 * 2;
  float* h45 = (float*)(ws + off);                      off += (size_t)2048 * 512 * 4;
  float* wT6 = (float*)(ws + off);                      off += (size_t)512 * 64 * 4;

  hipLaunchKernelGGL(transpose_kernel, dim3(32), dim3(256), 0, stream, fc6w, wT6, 64, 512);
  hipLaunchKernelGGL(fused_kernel, dim3(2048), dim3(512), 0, stream,
                     x, adj, w1, w2, alpha, bin_score,
                     fc2w, fc2b, fc3w, fc3b,
                     ln1g, ln1b, ln2g, ln2b, lnadj, lnfeats);
  hipLaunchKernelGGL(gemm_mfma_kernel, dim3(32, 4), dim3(256), 0, stream,
                     lnadj, fc4w, fc4b, h45, 4096, 512, 0);
  hipLaunchKernelGGL(gemm_mfma_kernel, dim3(32, 4), dim3(256), 0, stream,
                     lnfeats, fc5w, fc5b, h45, 1024, 512, 256);
  hipLaunchKernelGGL(head_kernel, dim3(256), dim3(256), 0, stream,
                     h45, wT6, fc6b, fc7w, fc7b, out);
}

// Round 15
// 311.779 us; speedup vs baseline: 1.3292x; 1.3292x over previous
//
#include <hip/hip_runtime.h>
#include <hip/hip_bf16.h>
#include <hip/hip_fp16.h>

// Problem constants
#define B_   2048
#define NN   128    // NMAX
#define MM   64     // HN
#define HD_  128
#define IND  18
#define FD_  16

typedef unsigned int u32;
typedef _Float16 h2_t __attribute__((ext_vector_type(2)));
typedef __attribute__((ext_vector_type(8))) short bf16x8;
typedef __attribute__((ext_vector_type(4))) float f32x4;

__device__ __forceinline__ float fdot2f(u32 a, u32 b, float c) {
#if defined(__has_builtin)
#if __has_builtin(__builtin_amdgcn_fdot2)
  return __builtin_amdgcn_fdot2(__builtin_bit_cast(h2_t, a),
                                __builtin_bit_cast(h2_t, b), c, false);
#else
  h2_t x = __builtin_bit_cast(h2_t, a), y = __builtin_bit_cast(h2_t, b);
  return c + (float)x[0] * (float)y[0] + (float)x[1] * (float)y[1];
#endif
#else
  h2_t x = __builtin_bit_cast(h2_t, a), y = __builtin_bit_cast(h2_t, b);
  return c + (float)x[0] * (float)y[0] + (float)x[1] * (float)y[1];
#endif
}

__device__ __forceinline__ u32 pk2(float a, float b) {
#if defined(__has_builtin)
#if __has_builtin(__builtin_amdgcn_cvt_pkrtz)
  return __builtin_bit_cast(u32, __builtin_amdgcn_cvt_pkrtz(a, b));
#else
  __half ha = __float2half_rn(a), hb = __float2half_rn(b);
  return (u32)__half_as_ushort(ha) | ((u32)__half_as_ushort(hb) << 16);
#endif
#else
  __half ha = __float2half_rn(a), hb = __float2half_rn(b);
  return (u32)__half_as_ushort(ha) | ((u32)__half_as_ushort(hb) << 16);
#endif
}

__device__ __forceinline__ float rcpf_(float x) {
#if defined(__has_builtin)
#if __has_builtin(__builtin_amdgcn_rcpf)
  return __builtin_amdgcn_rcpf(x);
#else
  return 1.0f / x;
#endif
#else
  return 1.0f / x;
#endif
}

__device__ __forceinline__ float h_lo(u32 d) {
  return __half2float(__ushort_as_half((unsigned short)(d & 0xffffu)));
}
__device__ __forceinline__ float h_hi(u32 d) {
  return __half2float(__ushort_as_half((unsigned short)(d >> 16)));
}

__device__ __forceinline__ float bf2f(unsigned short u) {
  union { float f; u32 i; } z; z.i = ((u32)u) << 16; return z.f;
}
__device__ __forceinline__ unsigned short f2bf(float f) {
  union { float fv; u32 u; } z; z.fv = f;
  u32 lsb = (z.u >> 16) & 1u;
  return (unsigned short)((z.u + 0x7fffu + lsb) >> 16);
}
__device__ __forceinline__ u32 bfpk(float a, float b) {
  return (u32)f2bf(a) | ((u32)f2bf(b) << 16);
}
__device__ __forceinline__ bf16x8 ldfrag(const unsigned short* p) {
  return __builtin_bit_cast(bf16x8, *reinterpret_cast<const uint4*>(p));
}
__device__ __forceinline__ u32 comb2(u32 ps, u32 pf, float a, float na) {
  float r0 = a * bf2f((unsigned short)(ps & 0xffffu)) + na * bf2f((unsigned short)(pf & 0xffffu));
  float r1 = a * bf2f((unsigned short)(ps >> 16)) + na * bf2f((unsigned short)(pf >> 16));
  return (u32)f2bf(r0) | ((u32)f2bf(r1) << 16);
}

// ---------------------------------------------------------------------------
// FUSED kernel (R15 = R14 with launch_bounds (512,2)): one block per batch,
// 512 threads (8 waves). LDS 70.6 KB -> 2 blocks/CU = 16 waves/CU = 4/SIMD.
// (512,2) -> VGPR cap 128: fits the Sinkhorn K-register arrays (R13 needed
// 104 with identical bodies); R14's (512,4) capped at 64 and spilled (FETCH
// 83 -> 272 MB). Single-variable fix.
// ---------------------------------------------------------------------------
#define AP 136   // bf16 row pitch (272 B)

__launch_bounds__(512, 2)
__global__ void fused_kernel(const float* __restrict__ x,
                             const float* __restrict__ adj,
                             const float* __restrict__ w1,
                             const float* __restrict__ w2,
                             const float* __restrict__ alpha_p,
                             const float* __restrict__ bin_score,
                             const float* __restrict__ fc2w, const float* __restrict__ fc2b,
                             const float* __restrict__ fc3w, const float* __restrict__ fc3b,
                             const float* __restrict__ ln1g, const float* __restrict__ ln1b,
                             const float* __restrict__ ln2g, const float* __restrict__ ln2b,
                             unsigned short* __restrict__ lnadj,
                             unsigned short* __restrict__ lnfeats)
{
  __shared__ __align__(16) u32 Ksh[2][64 * 68];            // 34816 B (K then P)
  __shared__ __align__(16) u32 vhs[2][64];
  __shared__ __align__(16) u32 uhs[2][32];
  __shared__ __align__(16) unsigned short adjb[64 * AP];   // 17408 B
  __shared__ __align__(16) unsigned short Z1T[64 * AP];    // 17408 B
  __shared__ float red[32];

  const int tid = threadIdx.x;
  const int w8 = tid >> 6;          // wave 0..7
  const int lane = tid & 63;
  const int l15 = lane & 15, q = lane >> 4;
  const int b = blockIdx.x;

  // ======================= Phase A: scores -> K ==========================
  {
    const int sw = w8 & 1;            // stream
    const int qr = w8 >> 1;           // quarter 0..3
    const float* wm = sw ? w2 : w1;
    const float* fw = sw ? fc3w : fc2w;
    const float* fb = sw ? fc3b : fc2b;
    unsigned short* Kshh = reinterpret_cast<unsigned short*>(Ksh[sw]);
    unsigned short* actw = (w8 < 4) ? (Z1T + (size_t)w8 * (16 * AP))
                                    : (adjb + (size_t)(w8 - 4) * (16 * AP));

    uint4 wA[4][4];
    #pragma unroll
    for (int at = 0; at < 4; ++at) {
      const float* wrow = wm + (size_t)(16 * at + l15) * 128;
      #pragma unroll
      for (int kt = 0; kt < 4; ++kt) {
        float4 va = *reinterpret_cast<const float4*>(wrow + 32 * kt + 8 * q);
        float4 vb = *reinterpret_cast<const float4*>(wrow + 32 * kt + 8 * q + 4);
        wA[at][kt] = make_uint4(bfpk(va.x, va.y), bfpk(va.z, va.w),
                                bfpk(vb.x, vb.y), bfpk(vb.z, vb.w));
      }
    }
    uint4 fcwB[8];
    #pragma unroll
    for (int nt = 0; nt < 8; ++nt) {
      const int ch = 16 * nt + l15;
      uint4 o = make_uint4(0u, 0u, 0u, 0u);
      if (sw) {
        if (q < 2) {
          const float* fr = fw + (size_t)ch * 16 + 8 * q;
          float4 va = *reinterpret_cast<const float4*>(fr);
          float4 vb = *reinterpret_cast<const float4*>(fr + 4);
          o = make_uint4(bfpk(va.x, va.y), bfpk(va.z, va.w),
                         bfpk(vb.x, vb.y), bfpk(vb.z, vb.w));
        }
      } else {
        if (q == 0) o.x = bfpk(fw[ch * 2], fw[ch * 2 + 1]);
      }
      fcwB[nt] = o;
    }
    float bb[8];
    #pragma unroll
    for (int nt = 0; nt < 8; ++nt) bb[nt] = fb[16 * nt + l15];

    uint4 xa[2];
    #pragma unroll
    for (int mi = 0; mi < 2; ++mi) {
      const int node = 16 * (2 * qr + mi) + l15;
      const float* xp = x + ((size_t)b * NN + node) * IND + (sw ? 2 : 0);
      uint4 o = make_uint4(0u, 0u, 0u, 0u);
      if (sw) {
        if (q < 2) {
          float2 p0 = *reinterpret_cast<const float2*>(xp + 8 * q);
          float2 p1 = *reinterpret_cast<const float2*>(xp + 8 * q + 2);
          float2 p2 = *reinterpret_cast<const float2*>(xp + 8 * q + 4);
          float2 p3 = *reinterpret_cast<const float2*>(xp + 8 * q + 6);
          o = make_uint4(bfpk(p0.x, p0.y), bfpk(p1.x, p1.y),
                         bfpk(p2.x, p2.y), bfpk(p3.x, p3.y));
        }
      } else {
        if (q == 0) {
          float2 p0 = *reinterpret_cast<const float2*>(xp);
          o.x = bfpk(p0.x, p0.y);
        }
      }
      xa[mi] = o;
    }

    #pragma unroll
    for (int mi = 0; mi < 2; ++mi) {
      const int mt = 2 * qr + mi;
      f32x4 acc[8];
      #pragma unroll
      for (int nt = 0; nt < 8; ++nt)
        acc[nt] = __builtin_amdgcn_mfma_f32_16x16x32_bf16(
            __builtin_bit_cast(bf16x8, xa[mi]), __builtin_bit_cast(bf16x8, fcwB[nt]),
            f32x4{0.f, 0.f, 0.f, 0.f}, 0, 0, 0);
      #pragma unroll
      for (int nt = 0; nt < 8; ++nt) {
        #pragma unroll
        for (int r = 0; r < 4; ++r) {
          float v = fmaxf(acc[nt][r] + bb[nt], 0.0f);
          actw[(4 * q + r) * AP + 16 * nt + l15] = f2bf(v);
        }
      }
      uint4 sB[4];
      #pragma unroll
      for (int kt = 0; kt < 4; ++kt)
        sB[kt] = *reinterpret_cast<const uint4*>(&actw[l15 * AP + 32 * kt + 8 * q]);
      #pragma unroll
      for (int at = 0; at < 4; ++at) {
        f32x4 sa = f32x4{0.f, 0.f, 0.f, 0.f};
        #pragma unroll
        for (int kt = 0; kt < 4; ++kt)
          sa = __builtin_amdgcn_mfma_f32_16x16x32_bf16(
              __builtin_bit_cast(bf16x8, wA[at][kt]), __builtin_bit_cast(bf16x8, sB[kt]),
              sa, 0, 0, 0);
        #pragma unroll
        for (int r = 0; r < 4; ++r) {
          float kv = fminf(__expf(fmaxf(sa[r], 0.0f)), 60000.0f);
          Kshh[(16 * at + 4 * q + r) * AP + 16 * mt + l15] =
              __half_as_ushort(__float2half_rn(kv));
        }
      }
    }
  }
  __syncthreads();   // Ksh[0..1] complete; Z1T/adjb scratch dead

  const float ebs = __expf(bin_score[0]);

  // ======= Phase B: Sinkhorn (waves 0,1) | adj h0 staging (waves 2-7) ====
  if (w8 < 2) {
    const int l = lane;
    u32* Ks = Ksh[w8];
    u32 kr[64];
    #pragma unroll
    for (int t = 0; t < 16; ++t) {
      uint4 kv = *reinterpret_cast<const uint4*>(Ks + l * 68 + 4 * t);
      kr[4 * t + 0] = kv.x; kr[4 * t + 1] = kv.y;
      kr[4 * t + 2] = kv.z; kr[4 * t + 3] = kv.w;
    }
    u32 kta[32], ktb[32];
    #pragma unroll
    for (int j = 0; j < 32; ++j) {
      u32 d0 = Ks[(2 * j) * 68 + l];
      u32 d1 = Ks[(2 * j + 1) * 68 + l];
      kta[j] = (d0 & 0xffffu) | (d1 << 16);
      ktb[j] = (d0 >> 16) | (d1 & 0xffff0000u);
    }

    u32* vh = vhs[w8];
    u32* uh = uhs[w8];
    vh[l] = 0x3C003C00u;
    float v128 = 1.0f, sum_v = 129.0f;
    float u_old = 0.0f, vo0 = 1.0f, vo1 = 1.0f;
    float ur = 0.0f;
    const float TOL = 1.5e-3f;

    for (int it = 0; it < 100; ++it) {
      const float u64v = 128.0f * rcpf_(ebs * sum_v);
      float a0 = ebs * v128, a1 = 0.f, a2 = 0.f, a3 = 0.f;
      const uint4* vh4 = reinterpret_cast<const uint4*>(vh);
      #pragma unroll
      for (int t = 0; t < 16; ++t) {
        uint4 vvv = vh4[t];
        a0 = fdot2f(kr[4 * t + 0], vvv.x, a0);
        a1 = fdot2f(kr[4 * t + 1], vvv.y, a1);
        a2 = fdot2f(kr[4 * t + 2], vvv.z, a2);
        a3 = fdot2f(kr[4 * t + 3], vvv.w, a3);
      }
      float urn = rcpf_((a0 + a1) + (a2 + a3));
      float m1 = fabsf(urn - u_old) - TOL * urn;
      u_old = urn; ur = urn;
      float su = urn;
      su += __shfl_xor(su, 1);  su += __shfl_xor(su, 2);
      su += __shfl_xor(su, 4);  su += __shfl_xor(su, 8);
      su += __shfl_xor(su, 16); su += __shfl_xor(su, 32);
      const float sum_u = su + u64v;
      const float v128n = 64.0f * rcpf_(ebs * sum_u);
      float upr = __shfl_xor(urn, 1);
      if (!(l & 1)) uh[l >> 1] = pk2(urn, upr);
      float c0a = ebs * u64v, c0b = 0.f, c1a = ebs * u64v, c1b = 0.f;
      const uint4* uh4 = reinterpret_cast<const uint4*>(uh);
      #pragma unroll
      for (int t = 0; t < 8; ++t) {
        uint4 uu = uh4[t];
        c0a = fdot2f(kta[4 * t + 0], uu.x, c0a);
        c0b = fdot2f(kta[4 * t + 1], uu.y, c0b);
        c0a = fdot2f(kta[4 * t + 2], uu.z, c0a);
        c0b = fdot2f(kta[4 * t + 3], uu.w, c0b);
        c1a = fdot2f(ktb[4 * t + 0], uu.x, c1a);
        c1b = fdot2f(ktb[4 * t + 1], uu.y, c1b);
        c1a = fdot2f(ktb[4 * t + 2], uu.z, c1a);
        c1b = fdot2f(ktb[4 * t + 3], uu.w, c1b);
      }
      float v0n = rcpf_(c0a + c0b);
      float v1n = rcpf_(c1a + c1b);
      float m2 = fabsf(v0n - vo0) - TOL * v0n;
      float m3 = fabsf(v1n - vo1) - TOL * v1n;
      vo0 = v0n; vo1 = v1n;
      vh[l] = pk2(v0n, v1n);
      float sv = v0n + v1n;
      sv += __shfl_xor(sv, 1);  sv += __shfl_xor(sv, 2);
      sv += __shfl_xor(sv, 4);  sv += __shfl_xor(sv, 8);
      sv += __shfl_xor(sv, 16); sv += __shfl_xor(sv, 32);
      sum_v = sv + v128n;
      v128 = v128n;
      float mcond = fmaxf(m1, fmaxf(m2, m3));
      if (__all(mcond <= 0.0f)) break;
    }

    // P = K*u*v bf16 in place over Ksh[w8]
    {
      const uint4* vh4 = reinterpret_cast<const uint4*>(vh);
      #pragma unroll
      for (int t = 0; t < 16; ++t) {
        uint4 vvv = vh4[t];
        u32 o0 = bfpk(h_lo(kr[4 * t + 0]) * ur * h_lo(vvv.x),
                      h_hi(kr[4 * t + 0]) * ur * h_hi(vvv.x));
        u32 o1 = bfpk(h_lo(kr[4 * t + 1]) * ur * h_lo(vvv.y),
                      h_hi(kr[4 * t + 1]) * ur * h_hi(vvv.y));
        u32 o2 = bfpk(h_lo(kr[4 * t + 2]) * ur * h_lo(vvv.z),
                      h_hi(kr[4 * t + 2]) * ur * h_hi(vvv.z));
        u32 o3 = bfpk(h_lo(kr[4 * t + 3]) * ur * h_lo(vvv.w),
                      h_hi(kr[4 * t + 3]) * ur * h_hi(vvv.w));
        *reinterpret_cast<uint4*>(&Ks[l * 68 + 4 * t]) = make_uint4(o0, o1, o2, o3);
      }
    }
  } else {
    // stage adj rows 0..63 -> adjb (384 threads)
    const float4* src = reinterpret_cast<const float4*>(adj + (size_t)b * (NN * NN));
    for (int i = tid - 128; i < 64 * 32; i += 384) {
      int row = i >> 5, c4 = i & 31;
      float4 v = src[i];
      u32 w0 = (u32)f2bf(v.x) | ((u32)f2bf(v.y) << 16);
      u32 w1 = (u32)f2bf(v.z) | ((u32)f2bf(v.w) << 16);
      *reinterpret_cast<uint2*>(&adjb[row * AP + c4 * 4]) = make_uint2(w0, w1);
    }
  }
  __syncthreads();   // P0,P1 in Ksh; adjb h0 staged

  // ======================= Phase C: align ================================
  const int g = w8 >> 1;     // rowgroup 0..3
  const int jh = w8 & 1;     // j-half
  const float aa = 1.0f / (1.0f + __expf(-alpha_p[0]));
  const float na = 1.0f - aa;
  for (int i = tid; i < 4096; i += 512) {
    int row = i >> 6, cd = i & 63;
    Ksh[0][row * 68 + cd] = comb2(Ksh[0][row * 68 + cd], Ksh[1][row * 68 + cd], aa, na);
  }
  __syncthreads();
  const unsigned short* Pc = reinterpret_cast<const unsigned short*>(Ksh[0]);

  // M1 half 0
  {
    f32x4 acch[2];
    acch[0] = f32x4{0.f, 0.f, 0.f, 0.f};
    acch[1] = f32x4{0.f, 0.f, 0.f, 0.f};
    #pragma unroll
    for (int kt = 0; kt < 4; ++kt) {
      const int d0 = 32 * kt + 8 * q;
      bf16x8 af = ldfrag(&adjb[(16 * g + l15) * AP + d0]);
      #pragma unroll
      for (int jj = 0; jj < 2; ++jj) {
        bf16x8 bf = ldfrag(&Pc[(16 * (2 * jh + jj) + l15) * AP + d0]);
        acch[jj] = __builtin_amdgcn_mfma_f32_16x16x32_bf16(af, bf, acch[jj], 0, 0, 0);
      }
    }
    __syncthreads();
    #pragma unroll
    for (int jj = 0; jj < 2; ++jj) {
      const int k = 16 * (2 * jh + jj) + l15;
      const int nbase = 16 * g + 4 * q;
      u32 w0 = (u32)f2bf(acch[jj][0]) | ((u32)f2bf(acch[jj][1]) << 16);
      u32 w1 = (u32)f2bf(acch[jj][2]) | ((u32)f2bf(acch[jj][3]) << 16);
      *reinterpret_cast<uint2*>(&Z1T[k * AP + nbase]) = make_uint2(w0, w1);
    }
  }
  __syncthreads();   // adjb h0 reads done

  // stage adj rows 64..127
  {
    const float4* src = reinterpret_cast<const float4*>(
        adj + (size_t)b * (NN * NN) + (size_t)64 * NN);
    for (int i = tid; i < 64 * 32; i += 512) {
      int row = i >> 5, c4 = i & 31;
      float4 v = src[i];
      u32 w0 = (u32)f2bf(v.x) | ((u32)f2bf(v.y) << 16);
      u32 w1 = (u32)f2bf(v.z) | ((u32)f2bf(v.w) << 16);
      *reinterpret_cast<uint2*>(&adjb[row * AP + c4 * 4]) = make_uint2(w0, w1);
    }
  }
  __syncthreads();

  // M1 half 1
  {
    f32x4 acch[2];
    acch[0] = f32x4{0.f, 0.f, 0.f, 0.f};
    acch[1] = f32x4{0.f, 0.f, 0.f, 0.f};
    #pragma unroll
    for (int kt = 0; kt < 4; ++kt) {
      const int d0 = 32 * kt + 8 * q;
      bf16x8 af = ldfrag(&adjb[(16 * g + l15) * AP + d0]);
      #pragma unroll
      for (int jj = 0; jj < 2; ++jj) {
        bf16x8 bf = ldfrag(&Pc[(16 * (2 * jh + jj) + l15) * AP + d0]);
        acch[jj] = __builtin_amdgcn_mfma_f32_16x16x32_bf16(af, bf, acch[jj], 0, 0, 0);
      }
    }
    #pragma unroll
    for (int jj = 0; jj < 2; ++jj) {
      const int k = 16 * (2 * jh + jj) + l15;
      const int nbase = 64 + 16 * g + 4 * q;
      u32 w0 = (u32)f2bf(acch[jj][0]) | ((u32)f2bf(acch[jj][1]) << 16);
      u32 w1 = (u32)f2bf(acch[jj][2]) | ((u32)f2bf(acch[jj][3]) << 16);
      *reinterpret_cast<uint2*>(&Z1T[k * AP + nbase]) = make_uint2(w0, w1);
    }
  }
  __syncthreads();   // Z1T complete; adjb free

  // stage xfT into adjb tail
  unsigned short* xfT = adjb + 48 * AP;
  for (int i = tid; i < 2048; i += 512) {
    int n = i & 127, f = i >> 7;
    xfT[f * AP + n] = f2bf(x[((size_t)b * NN + n) * IND + 2 + f]);
  }
  __syncthreads();

  // M2 (j-half) + M3 (jh==0 only)
  f32x4 acc2[2];
  acc2[0] = f32x4{0.f, 0.f, 0.f, 0.f};
  acc2[1] = f32x4{0.f, 0.f, 0.f, 0.f};
  f32x4 acc3 = f32x4{0.f, 0.f, 0.f, 0.f};
  #pragma unroll
  for (int nt = 0; nt < 4; ++nt) {
    const int n0 = 32 * nt + 8 * q;
    bf16x8 af = ldfrag(&Pc[(16 * g + l15) * AP + n0]);
    #pragma unroll
    for (int jj = 0; jj < 2; ++jj) {
      bf16x8 bv = ldfrag(&Z1T[(16 * (2 * jh + jj) + l15) * AP + n0]);
      acc2[jj] = __builtin_amdgcn_mfma_f32_16x16x32_bf16(af, bv, acc2[jj], 0, 0, 0);
    }
    if (jh == 0) {
      bf16x8 bx = ldfrag(&xfT[l15 * AP + n0]);
      acc3 = __builtin_amdgcn_mfma_f32_16x16x32_bf16(af, bx, acc3, 0, 0, 0);
    }
  }

  // LN reductions (8 waves)
  {
    float s1 = 0.f, q1 = 0.f, s2 = 0.f, q2 = 0.f;
    #pragma unroll
    for (int jj = 0; jj < 2; ++jj)
      #pragma unroll
      for (int r = 0; r < 4; ++r) { float v = acc2[jj][r]; s1 += v; q1 += v * v; }
    if (jh == 0) {
      #pragma unroll
      for (int r = 0; r < 4; ++r) { float v = acc3[r]; s2 += v; q2 += v * v; }
    }
    #pragma unroll
    for (int off = 1; off < 64; off <<= 1) {
      s1 += __shfl_xor(s1, off); q1 += __shfl_xor(q1, off);
      s2 += __shfl_xor(s2, off); q2 += __shfl_xor(q2, off);
    }
    if (lane == 0) { red[w8] = s1; red[8 + w8] = q1; red[16 + w8] = s2; red[24 + w8] = q2; }
  }
  __syncthreads();
  float S1 = 0.f, Q1 = 0.f, S2 = 0.f, Q2 = 0.f;
  #pragma unroll
  for (int i = 0; i < 8; ++i) {
    S1 += red[i]; Q1 += red[8 + i]; S2 += red[16 + i]; Q2 += red[24 + i];
  }
  const float mean1 = S1 * (1.0f / 4096.0f);
  const float rstd1 = rsqrtf(Q1 * (1.0f / 4096.0f) - mean1 * mean1 + 1e-5f);
  const float mean2 = S2 * (1.0f / 1024.0f);
  const float rstd2 = rsqrtf(Q2 * (1.0f / 1024.0f) - mean2 * mean2 + 1e-5f);

  // normalize + bounce (ob1 = adjb head; ob2 = Z1T head — after barrier)
  __syncthreads();
  unsigned short* ob1 = adjb;
  unsigned short* ob2 = Z1T;
  #pragma unroll
  for (int jj = 0; jj < 2; ++jj) {
    const int k = 16 * (2 * jh + jj) + l15;
    #pragma unroll
    for (int r = 0; r < 4; ++r) {
      const int m = 16 * g + 4 * q + r;
      const int pos = m * 64 + k;
      float vv2 = (acc2[jj][r] - mean1) * rstd1 * ln1g[pos] + ln1b[pos];
      ob1[pos] = f2bf(vv2);
    }
  }
  if (jh == 0) {
    const int f = l15;
    #pragma unroll
    for (int r = 0; r < 4; ++r) {
      const int m = 16 * g + 4 * q + r;
      const int pos = m * 16 + f;
      float vv2 = (acc3[r] - mean2) * rstd2 * ln2g[pos] + ln2b[pos];
      ob2[pos] = f2bf(vv2);
    }
  }
  __syncthreads();
  {
    const uint4* sp = reinterpret_cast<const uint4*>(ob1);
    uint4* dp = reinterpret_cast<uint4*>(lnadj + (size_t)b * 4096);
    for (int i = tid; i < 512; i += 512) dp[i] = sp[i];
    if (tid < 128)
      reinterpret_cast<uint4*>(lnfeats + (size_t)b * 1024)[tid] =
          reinterpret_cast<const uint4*>(ob2)[tid];
  }
}

// ---------------------------------------------------------------------------
// Kernel C (MFMA): unchanged.
// ---------------------------------------------------------------------------
#define GP 72
__launch_bounds__(256, 2)
__global__ void gemm_mfma_kernel(const unsigned short* __restrict__ A,
                                 const float* __restrict__ W,
                                 const float* __restrict__ bias,
                                 float* __restrict__ C,
                                 int K, int ldc, int coff)
{
  __shared__ __align__(16) unsigned short At[64 * GP];
  __shared__ __align__(16) unsigned short Wt[64 * GP];
  const int tid = threadIdx.x;
  const int m0 = blockIdx.x * 64;
  const int n0 = blockIdx.y * 64;
  const int w = tid >> 6, lane = tid & 63;
  const int l15 = lane & 15, q = lane >> 4;
  const int srow = tid >> 2, sko = (tid & 3) * 16;

  f32x4 acc[4];
  #pragma unroll
  for (int j = 0; j < 4; ++j) acc[j] = f32x4{0.f, 0.f, 0.f, 0.f};

  for (int kc = 0; kc < K; kc += 64) {
    __syncthreads();
    {
      const unsigned short* ap = &A[(size_t)(m0 + srow) * K + kc + sko];
      *reinterpret_cast<uint4*>(&At[srow * GP + sko]) =
          *reinterpret_cast<const uint4*>(ap);
      *reinterpret_cast<uint4*>(&At[srow * GP + sko + 8]) =
          *reinterpret_cast<const uint4*>(ap + 8);
      const float* wp = &W[(size_t)(n0 + srow) * K + kc + sko];
      const float4 v0 = reinterpret_cast<const float4*>(wp)[0];
      const float4 v1 = reinterpret_cast<const float4*>(wp)[1];
      const float4 v2 = reinterpret_cast<const float4*>(wp)[2];
      const float4 v3 = reinterpret_cast<const float4*>(wp)[3];
      uint4 o0, o1;
      o0.x = (u32)f2bf(v0.x) | ((u32)f2bf(v0.y) << 16);
      o0.y = (u32)f2bf(v0.z) | ((u32)f2bf(v0.w) << 16);
      o0.z = (u32)f2bf(v1.x) | ((u32)f2bf(v1.y) << 16);
      o0.w = (u32)f2bf(v1.z) | ((u32)f2bf(v1.w) << 16);
      o1.x = (u32)f2bf(v2.x) | ((u32)f2bf(v2.y) << 16);
      o1.y = (u32)f2bf(v2.z) | ((u32)f2bf(v2.w) << 16);
      o1.z = (u32)f2bf(v3.x) | ((u32)f2bf(v3.y) << 16);
      o1.w = (u32)f2bf(v3.z) | ((u32)f2bf(v3.w) << 16);
      *reinterpret_cast<uint4*>(&Wt[srow * GP + sko]) = o0;
      *reinterpret_cast<uint4*>(&Wt[srow * GP + sko + 8]) = o1;
    }
    __syncthreads();
    #pragma unroll
    for (int s = 0; s < 2; ++s) {
      bf16x8 af = ldfrag(&At[(16 * w + l15) * GP + 32 * s + 8 * q]);
      #pragma unroll
      for (int j = 0; j < 4; ++j) {
        bf16x8 bf = ldfrag(&Wt[(16 * j + l15) * GP + 32 * s + 8 * q]);
        acc[j] = __builtin_amdgcn_mfma_f32_16x16x32_bf16(af, bf, acc[j], 0, 0, 0);
      }
    }
  }
  #pragma unroll
  for (int j = 0; j < 4; ++j) {
    const int col = n0 + 16 * j + l15;
    const float bb = bias[col];
    #pragma unroll
    for (int r = 0; r < 4; ++r) {
      const int m = m0 + 16 * w + 4 * q + r;
      C[(size_t)m * ldc + coff + col] = fmaxf(acc[j][r] + bb, 0.0f);
    }
  }
}

// ---------------------------------------------------------------------------
// Kernel D: unchanged (8 rows/block).
// ---------------------------------------------------------------------------
__launch_bounds__(256)
__global__ void head_kernel(const float* __restrict__ h45,
                            const float* __restrict__ wT6,   // [512][64]
                            const float* __restrict__ b6,
                            const float* __restrict__ w7,    // [10][64]
                            const float* __restrict__ b7,
                            float* __restrict__ out)
{
  __shared__ float row[8][512];
  __shared__ float h6[8][64];
  __shared__ float zb[8][12];
  const int tid = threadIdx.x;
  const int r0 = blockIdx.x * 8;
  for (int i = tid; i < 8 * 128; i += 256) {
    int r = i >> 7, c4 = i & 127;
    *reinterpret_cast<float4*>(&row[r][c4 * 4]) =
        reinterpret_cast<const float4*>(h45 + (size_t)(r0 + r) * 512)[c4];
  }
  __syncthreads();
  const int o = tid & 63, rg = tid >> 6;
  float a0 = b6[o], a1 = a0;
  #pragma unroll 8
  for (int k = 0; k < 512; ++k) {
    float wv = wT6[k * 64 + o];
    a0 += row[rg][k] * wv;
    a1 += row[rg + 4][k] * wv;
  }
  h6[rg][o] = fmaxf(a0, 0.0f);
  h6[rg + 4][o] = fmaxf(a1, 0.0f);
  __syncthreads();
  if (tid < 80) {
    int r = tid / 10, c = tid - r * 10;
    float z = b7[c];
    #pragma unroll
    for (int k = 0; k < 64; ++k) z += h6[r][k] * w7[c * 64 + k];
    zb[r][c] = z;
  }
  __syncthreads();
  if (tid < 80) {
    int r = tid / 10, c = tid - r * 10;
    float mx = zb[r][0];
    #pragma unroll
    for (int j = 1; j < 10; ++j) mx = fmaxf(mx, zb[r][j]);
    float se = 0.f;
    #pragma unroll
    for (int j = 0; j < 10; ++j) se += __expf(zb[r][j] - mx);
    out[(size_t)(r0 + r) * 10 + c] = zb[r][c] - mx - __logf(se);
  }
}

__global__ void transpose_kernel(const float* __restrict__ in, float* __restrict__ outp,
                                 int R, int Cc)
{
  int idx = blockIdx.x * blockDim.x + threadIdx.x;
  int total = R * Cc;
  for (; idx < total; idx += gridDim.x * blockDim.x) {
    int rr = idx / Cc, cc = idx - rr * Cc;
    outp[cc * R + rr] = in[idx];
  }
}

// ---------------------------------------------------------------------------
extern "C" void kernel_launch(void* const* d_in, const int* in_sizes, int n_in,
                              void* d_out, int out_size, void* d_ws, size_t ws_size,
                              hipStream_t stream)
{
  (void)in_sizes; (void)n_in; (void)out_size; (void)ws_size;
  const float* x    = (const float*)d_in[0];
  const float* adj  = (const float*)d_in[1];
  const float* w1   = (const float*)d_in[2];
  const float* w2   = (const float*)d_in[3];
  const float* alpha = (const float*)d_in[4];
  const float* bin_score = (const float*)d_in[5];
  const float* fc2w = (const float*)d_in[6];
  const float* fc2b = (const float*)d_in[7];
  const float* fc3w = (const float*)d_in[8];
  const float* fc3b = (const float*)d_in[9];
  const float* ln1g = (const float*)d_in[10];
  const float* ln1b = (const float*)d_in[11];
  const float* fc4w = (const float*)d_in[12];
  const float* fc4b = (const float*)d_in[13];
  const float* ln2g = (const float*)d_in[14];
  const float* ln2b = (const float*)d_in[15];
  const float* fc5w = (const float*)d_in[16];
  const float* fc5b = (const float*)d_in[17];
  const float* fc6w = (const float*)d_in[18];
  const float* fc6b = (const float*)d_in[19];
  const float* fc7w = (const float*)d_in[20];
  const float* fc7b = (const float*)d_in[21];
  float* out = (float*)d_out;

  char* ws = (char*)d_ws;
  size_t off = 0;
  unsigned short* lnadj = (unsigned short*)(ws + off);  off += (size_t)2048 * 4096 * 2;
  unsigned short* lnfeats = (unsigned short*)(ws + off); off += (size_t)2048 * 1024 * 2;
  float* h45 = (float*)(ws + off);                      off += (size_t)2048 * 512 * 4;
  float* wT6 = (float*)(ws + off);                      off += (size_t)512 * 64 * 4;

  hipLaunchKernelGGL(transpose_kernel, dim3(32), dim3(256), 0, stream, fc6w, wT6, 64, 512);
  hipLaunchKernelGGL(fused_kernel, dim3(2048), dim3(512), 0, stream,
                     x, adj, w1, w2, alpha, bin_score,
                     fc2w, fc2b, fc3w, fc3b,
                     ln1g, ln1b, ln2g, ln2b, lnadj, lnfeats);
  hipLaunchKernelGGL(gemm_mfma_kernel, dim3(32, 4), dim3(256), 0, stream,
                     lnadj, fc4w, fc4b, h45, 4096, 512, 0);
  hipLaunchKernelGGL(gemm_mfma_kernel, dim3(32, 4), dim3(256), 0, stream,
                     lnfeats, fc5w, fc5b, h45, 1024, 512, 256);
  hipLaunchKernelGGL(head_kernel, dim3(256), dim3(256), 0, stream,
                     h45, wT6, fc6b, fc7w, fc7b, out);
}

// Round 16
// 206.051 us; speedup vs baseline: 2.0112x; 1.5131x over previous
//
#include <hip/hip_runtime.h>
#include <hip/hip_bf16.h>
#include <hip/hip_fp16.h>

// Problem constants
#define B_   2048
#define NN   128    // NMAX
#define MM   64     // HN
#define HD_  128
#define IND  18
#define FD_  16

typedef unsigned int u32;
typedef _Float16 h2_t __attribute__((ext_vector_type(2)));
typedef __attribute__((ext_vector_type(8))) short bf16x8;
typedef __attribute__((ext_vector_type(4))) float f32x4;

__device__ __forceinline__ float fdot2f(u32 a, u32 b, float c) {
#if defined(__has_builtin)
#if __has_builtin(__builtin_amdgcn_fdot2)
  return __builtin_amdgcn_fdot2(__builtin_bit_cast(h2_t, a),
                                __builtin_bit_cast(h2_t, b), c, false);
#else
  h2_t x = __builtin_bit_cast(h2_t, a), y = __builtin_bit_cast(h2_t, b);
  return c + (float)x[0] * (float)y[0] + (float)x[1] * (float)y[1];
#endif
#else
  h2_t x = __builtin_bit_cast(h2_t, a), y = __builtin_bit_cast(h2_t, b);
  return c + (float)x[0] * (float)y[0] + (float)x[1] * (float)y[1];
#endif
}

__device__ __forceinline__ u32 pk2(float a, float b) {
#if defined(__has_builtin)
#if __has_builtin(__builtin_amdgcn_cvt_pkrtz)
  return __builtin_bit_cast(u32, __builtin_amdgcn_cvt_pkrtz(a, b));
#else
  __half ha = __float2half_rn(a), hb = __float2half_rn(b);
  return (u32)__half_as_ushort(ha) | ((u32)__half_as_ushort(hb) << 16);
#endif
#else
  __half ha = __float2half_rn(a), hb = __float2half_rn(b);
  return (u32)__half_as_ushort(ha) | ((u32)__half_as_ushort(hb) << 16);
#endif
}

__device__ __forceinline__ float rcpf_(float x) {
#if defined(__has_builtin)
#if __has_builtin(__builtin_amdgcn_rcpf)
  return __builtin_amdgcn_rcpf(x);
#else
  return 1.0f / x;
#endif
#else
  return 1.0f / x;
#endif
}

__device__ __forceinline__ float h_lo(u32 d) {
  return __half2float(__ushort_as_half((unsigned short)(d & 0xffffu)));
}
__device__ __forceinline__ float h_hi(u32 d) {
  return __half2float(__ushort_as_half((unsigned short)(d >> 16)));
}

__device__ __forceinline__ float bf2f(unsigned short u) {
  union { float f; u32 i; } z; z.i = ((u32)u) << 16; return z.f;
}
__device__ __forceinline__ unsigned short f2bf(float f) {
  union { float fv; u32 u; } z; z.fv = f;
  u32 lsb = (z.u >> 16) & 1u;
  return (unsigned short)((z.u + 0x7fffu + lsb) >> 16);
}
__device__ __forceinline__ u32 bfpk(float a, float b) {
  return (u32)f2bf(a) | ((u32)f2bf(b) << 16);
}
__device__ __forceinline__ bf16x8 ldfrag(const unsigned short* p) {
  return __builtin_bit_cast(bf16x8, *reinterpret_cast<const uint4*>(p));
}
__device__ __forceinline__ u32 comb2(u32 ps, u32 pf, float a, float na) {
  float r0 = a * bf2f((unsigned short)(ps & 0xffffu)) + na * bf2f((unsigned short)(pf & 0xffffu));
  float r1 = a * bf2f((unsigned short)(ps >> 16)) + na * bf2f((unsigned short)(pf >> 16));
  return (u32)f2bf(r0) | ((u32)f2bf(r1) << 16);
}

// ---------------------------------------------------------------------------
// FUSED kernel (R13 verbatim — best measured config: 169.6us, 2 blocks/CU).
// One block per batch, 256 threads (4 waves).
// ---------------------------------------------------------------------------
#define AP 136   // bf16 row pitch (272 B)

__launch_bounds__(256, 2)
__global__ void fused_kernel(const float* __restrict__ x,
                             const float* __restrict__ adj,
                             const float* __restrict__ w1,
                             const float* __restrict__ w2,
                             const float* __restrict__ alpha_p,
                             const float* __restrict__ bin_score,
                             const float* __restrict__ fc2w, const float* __restrict__ fc2b,
                             const float* __restrict__ fc3w, const float* __restrict__ fc3b,
                             const float* __restrict__ ln1g, const float* __restrict__ ln1b,
                             const float* __restrict__ ln2g, const float* __restrict__ ln2b,
                             unsigned short* __restrict__ lnadj,
                             unsigned short* __restrict__ lnfeats)
{
  __shared__ __align__(16) u32 Ksh[2][64 * 68];            // 34816 B (K then P)
  __shared__ __align__(16) u32 vhs[2][64];
  __shared__ __align__(16) u32 uhs[2][32];
  __shared__ __align__(16) unsigned short adjb[64 * AP];   // 17408 B
  __shared__ __align__(16) unsigned short Z1T[64 * AP];    // 17408 B
  __shared__ float red[16];

  const int tid = threadIdx.x;
  const int wv = tid >> 6;
  const int lane = tid & 63;
  const int l15 = lane & 15, q = lane >> 4;
  const int b = blockIdx.x;

  // ======================= Phase A: scores -> K ==========================
  {
    const int sw = wv & 1;               // stream
    const int mtbase = (wv >> 1) * 4;    // slice half
    const float* wm = sw ? w2 : w1;
    const float* fw = sw ? fc3w : fc2w;
    const float* fb = sw ? fc3b : fc2b;
    unsigned short* Kshh = reinterpret_cast<unsigned short*>(Ksh[sw]);
    unsigned short* actw = Z1T + (size_t)wv * (16 * AP);   // per-wave scratch

    uint4 wA[4][4];
    #pragma unroll
    for (int at = 0; at < 4; ++at) {
      const float* wrow = wm + (size_t)(16 * at + l15) * 128;
      #pragma unroll
      for (int kt = 0; kt < 4; ++kt) {
        float4 va = *reinterpret_cast<const float4*>(wrow + 32 * kt + 8 * q);
        float4 vb = *reinterpret_cast<const float4*>(wrow + 32 * kt + 8 * q + 4);
        wA[at][kt] = make_uint4(bfpk(va.x, va.y), bfpk(va.z, va.w),
                                bfpk(vb.x, vb.y), bfpk(vb.z, vb.w));
      }
    }
    uint4 fcwB[8];
    #pragma unroll
    for (int nt = 0; nt < 8; ++nt) {
      const int ch = 16 * nt + l15;
      uint4 o = make_uint4(0u, 0u, 0u, 0u);
      if (sw) {
        if (q < 2) {
          const float* fr = fw + (size_t)ch * 16 + 8 * q;
          float4 va = *reinterpret_cast<const float4*>(fr);
          float4 vb = *reinterpret_cast<const float4*>(fr + 4);
          o = make_uint4(bfpk(va.x, va.y), bfpk(va.z, va.w),
                         bfpk(vb.x, vb.y), bfpk(vb.z, vb.w));
        }
      } else {
        if (q == 0) o.x = bfpk(fw[ch * 2], fw[ch * 2 + 1]);
      }
      fcwB[nt] = o;
    }
    float bb[8];
    #pragma unroll
    for (int nt = 0; nt < 8; ++nt) bb[nt] = fb[16 * nt + l15];

    uint4 xa[4];
    #pragma unroll
    for (int mi = 0; mi < 4; ++mi) {
      const int node = 16 * (mtbase + mi) + l15;
      const float* xp = x + ((size_t)b * NN + node) * IND + (sw ? 2 : 0);
      uint4 o = make_uint4(0u, 0u, 0u, 0u);
      if (sw) {
        if (q < 2) {
          float2 p0 = *reinterpret_cast<const float2*>(xp + 8 * q);
          float2 p1 = *reinterpret_cast<const float2*>(xp + 8 * q + 2);
          float2 p2 = *reinterpret_cast<const float2*>(xp + 8 * q + 4);
          float2 p3 = *reinterpret_cast<const float2*>(xp + 8 * q + 6);
          o = make_uint4(bfpk(p0.x, p0.y), bfpk(p1.x, p1.y),
                         bfpk(p2.x, p2.y), bfpk(p3.x, p3.y));
        }
      } else {
        if (q == 0) {
          float2 p0 = *reinterpret_cast<const float2*>(xp);
          o.x = bfpk(p0.x, p0.y);
        }
      }
      xa[mi] = o;
    }

    #pragma unroll
    for (int mi = 0; mi < 4; ++mi) {
      const int mt = mtbase + mi;
      f32x4 acc[8];
      #pragma unroll
      for (int nt = 0; nt < 8; ++nt)
        acc[nt] = __builtin_amdgcn_mfma_f32_16x16x32_bf16(
            __builtin_bit_cast(bf16x8, xa[mi]), __builtin_bit_cast(bf16x8, fcwB[nt]),
            f32x4{0.f, 0.f, 0.f, 0.f}, 0, 0, 0);
      #pragma unroll
      for (int nt = 0; nt < 8; ++nt) {
        #pragma unroll
        for (int r = 0; r < 4; ++r) {
          float v = fmaxf(acc[nt][r] + bb[nt], 0.0f);
          actw[(4 * q + r) * AP + 16 * nt + l15] = f2bf(v);
        }
      }
      uint4 sB[4];
      #pragma unroll
      for (int kt = 0; kt < 4; ++kt)
        sB[kt] = *reinterpret_cast<const uint4*>(&actw[l15 * AP + 32 * kt + 8 * q]);
      #pragma unroll
      for (int at = 0; at < 4; ++at) {
        f32x4 sa = f32x4{0.f, 0.f, 0.f, 0.f};
        #pragma unroll
        for (int kt = 0; kt < 4; ++kt)
          sa = __builtin_amdgcn_mfma_f32_16x16x32_bf16(
              __builtin_bit_cast(bf16x8, wA[at][kt]), __builtin_bit_cast(bf16x8, sB[kt]),
              sa, 0, 0, 0);
        #pragma unroll
        for (int r = 0; r < 4; ++r) {
          float kv = fminf(__expf(fmaxf(sa[r], 0.0f)), 60000.0f);
          Kshh[(16 * at + 4 * q + r) * AP + 16 * mt + l15] =
              __half_as_ushort(__float2half_rn(kv));
        }
      }
    }
  }
  __syncthreads();   // Ksh[0..1] complete; actL (Z1T) dead

  const float ebs = __expf(bin_score[0]);

  // ============== Phase B: Sinkhorn (waves 0-1) | adj h0 (waves 2-3) =====
  if (wv < 2) {
    const int l = lane;
    u32* Ks = Ksh[wv];
    u32 kr[64];
    #pragma unroll
    for (int t = 0; t < 16; ++t) {
      uint4 kv = *reinterpret_cast<const uint4*>(Ks + l * 68 + 4 * t);
      kr[4 * t + 0] = kv.x; kr[4 * t + 1] = kv.y;
      kr[4 * t + 2] = kv.z; kr[4 * t + 3] = kv.w;
    }
    u32 kta[32], ktb[32];
    #pragma unroll
    for (int j = 0; j < 32; ++j) {
      u32 d0 = Ks[(2 * j) * 68 + l];
      u32 d1 = Ks[(2 * j + 1) * 68 + l];
      kta[j] = (d0 & 0xffffu) | (d1 << 16);
      ktb[j] = (d0 >> 16) | (d1 & 0xffff0000u);
    }

    u32* vh = vhs[wv];
    u32* uh = uhs[wv];
    vh[l] = 0x3C003C00u;
    float v128 = 1.0f, sum_v = 129.0f;
    float u_old = 0.0f, vo0 = 1.0f, vo1 = 1.0f;
    float ur = 0.0f;
    const float TOL = 1.5e-3f;

    for (int it = 0; it < 100; ++it) {
      const float u64v = 128.0f * rcpf_(ebs * sum_v);
      float a0 = ebs * v128, a1 = 0.f, a2 = 0.f, a3 = 0.f;
      const uint4* vh4 = reinterpret_cast<const uint4*>(vh);
      #pragma unroll
      for (int t = 0; t < 16; ++t) {
        uint4 vvv = vh4[t];
        a0 = fdot2f(kr[4 * t + 0], vvv.x, a0);
        a1 = fdot2f(kr[4 * t + 1], vvv.y, a1);
        a2 = fdot2f(kr[4 * t + 2], vvv.z, a2);
        a3 = fdot2f(kr[4 * t + 3], vvv.w, a3);
      }
      float urn = rcpf_((a0 + a1) + (a2 + a3));
      float m1 = fabsf(urn - u_old) - TOL * urn;
      u_old = urn; ur = urn;
      float su = urn;
      su += __shfl_xor(su, 1);  su += __shfl_xor(su, 2);
      su += __shfl_xor(su, 4);  su += __shfl_xor(su, 8);
      su += __shfl_xor(su, 16); su += __shfl_xor(su, 32);
      const float sum_u = su + u64v;
      const float v128n = 64.0f * rcpf_(ebs * sum_u);
      float upr = __shfl_xor(urn, 1);
      if (!(l & 1)) uh[l >> 1] = pk2(urn, upr);
      float c0a = ebs * u64v, c0b = 0.f, c1a = ebs * u64v, c1b = 0.f;
      const uint4* uh4 = reinterpret_cast<const uint4*>(uh);
      #pragma unroll
      for (int t = 0; t < 8; ++t) {
        uint4 uu = uh4[t];
        c0a = fdot2f(kta[4 * t + 0], uu.x, c0a);
        c0b = fdot2f(kta[4 * t + 1], uu.y, c0b);
        c0a = fdot2f(kta[4 * t + 2], uu.z, c0a);
        c0b = fdot2f(kta[4 * t + 3], uu.w, c0b);
        c1a = fdot2f(ktb[4 * t + 0], uu.x, c1a);
        c1b = fdot2f(ktb[4 * t + 1], uu.y, c1b);
        c1a = fdot2f(ktb[4 * t + 2], uu.z, c1a);
        c1b = fdot2f(ktb[4 * t + 3], uu.w, c1b);
      }
      float v0n = rcpf_(c0a + c0b);
      float v1n = rcpf_(c1a + c1b);
      float m2 = fabsf(v0n - vo0) - TOL * v0n;
      float m3 = fabsf(v1n - vo1) - TOL * v1n;
      vo0 = v0n; vo1 = v1n;
      vh[l] = pk2(v0n, v1n);
      float sv = v0n + v1n;
      sv += __shfl_xor(sv, 1);  sv += __shfl_xor(sv, 2);
      sv += __shfl_xor(sv, 4);  sv += __shfl_xor(sv, 8);
      sv += __shfl_xor(sv, 16); sv += __shfl_xor(sv, 32);
      sum_v = sv + v128n;
      v128 = v128n;
      float mcond = fmaxf(m1, fmaxf(m2, m3));
      if (__all(mcond <= 0.0f)) break;
    }

    // P = K*u*v (bf16) IN PLACE over Ksh[wv]
    {
      const uint4* vh4 = reinterpret_cast<const uint4*>(vh);
      #pragma unroll
      for (int t = 0; t < 16; ++t) {
        uint4 vvv = vh4[t];
        u32 o0 = bfpk(h_lo(kr[4 * t + 0]) * ur * h_lo(vvv.x),
                      h_hi(kr[4 * t + 0]) * ur * h_hi(vvv.x));
        u32 o1 = bfpk(h_lo(kr[4 * t + 1]) * ur * h_lo(vvv.y),
                      h_hi(kr[4 * t + 1]) * ur * h_hi(vvv.y));
        u32 o2 = bfpk(h_lo(kr[4 * t + 2]) * ur * h_lo(vvv.z),
                      h_hi(kr[4 * t + 2]) * ur * h_hi(vvv.z));
        u32 o3 = bfpk(h_lo(kr[4 * t + 3]) * ur * h_lo(vvv.w),
                      h_hi(kr[4 * t + 3]) * ur * h_hi(vvv.w));
        *reinterpret_cast<uint4*>(&Ks[l * 68 + 4 * t]) = make_uint4(o0, o1, o2, o3);
      }
    }
  } else {
    // stage adj rows 0..63 -> adjb (128 threads)
    const float4* src = reinterpret_cast<const float4*>(adj + (size_t)b * (NN * NN));
    for (int i = tid - 128; i < 64 * 32; i += 128) {
      int row = i >> 5, c4 = i & 31;
      float4 v = src[i];
      u32 w0 = (u32)f2bf(v.x) | ((u32)f2bf(v.y) << 16);
      u32 w1 = (u32)f2bf(v.z) | ((u32)f2bf(v.w) << 16);
      *reinterpret_cast<uint2*>(&adjb[row * AP + c4 * 4]) = make_uint2(w0, w1);
    }
  }
  __syncthreads();   // P0,P1 in Ksh; adjb h0 staged

  // ======================= Phase C: align ================================
  const float aa = 1.0f / (1.0f + __expf(-alpha_p[0]));
  const float na = 1.0f - aa;
  for (int i = tid; i < 4096; i += 256) {
    int row = i >> 6, cd = i & 63;
    Ksh[0][row * 68 + cd] = comb2(Ksh[0][row * 68 + cd], Ksh[1][row * 68 + cd], aa, na);
  }
  __syncthreads();
  const unsigned short* Pc = reinterpret_cast<const unsigned short*>(Ksh[0]);

  // M1 half 0
  {
    f32x4 acch[4];
    #pragma unroll
    for (int j = 0; j < 4; ++j) acch[j] = f32x4{0.f, 0.f, 0.f, 0.f};
    #pragma unroll
    for (int kt = 0; kt < 4; ++kt) {
      const int d0 = 32 * kt + 8 * q;
      bf16x8 af = ldfrag(&adjb[(16 * wv + l15) * AP + d0]);
      #pragma unroll
      for (int j = 0; j < 4; ++j) {
        bf16x8 bf = ldfrag(&Pc[(16 * j + l15) * AP + d0]);
        acch[j] = __builtin_amdgcn_mfma_f32_16x16x32_bf16(af, bf, acch[j], 0, 0, 0);
      }
    }
    __syncthreads();
    #pragma unroll
    for (int j = 0; j < 4; ++j) {
      const int k = 16 * j + l15;
      const int nbase = 16 * wv + 4 * q;
      u32 w0 = (u32)f2bf(acch[j][0]) | ((u32)f2bf(acch[j][1]) << 16);
      u32 w1 = (u32)f2bf(acch[j][2]) | ((u32)f2bf(acch[j][3]) << 16);
      *reinterpret_cast<uint2*>(&Z1T[k * AP + nbase]) = make_uint2(w0, w1);
    }
  }
  __syncthreads();   // adjb h0 reads done

  // stage adj rows 64..127
  {
    const float4* src = reinterpret_cast<const float4*>(
        adj + (size_t)b * (NN * NN) + (size_t)64 * NN);
    for (int i = tid; i < 64 * 32; i += 256) {
      int row = i >> 5, c4 = i & 31;
      float4 v = src[i];
      u32 w0 = (u32)f2bf(v.x) | ((u32)f2bf(v.y) << 16);
      u32 w1 = (u32)f2bf(v.z) | ((u32)f2bf(v.w) << 16);
      *reinterpret_cast<uint2*>(&adjb[row * AP + c4 * 4]) = make_uint2(w0, w1);
    }
  }
  __syncthreads();

  // M1 half 1
  {
    f32x4 acch[4];
    #pragma unroll
    for (int j = 0; j < 4; ++j) acch[j] = f32x4{0.f, 0.f, 0.f, 0.f};
    #pragma unroll
    for (int kt = 0; kt < 4; ++kt) {
      const int d0 = 32 * kt + 8 * q;
      bf16x8 af = ldfrag(&adjb[(16 * wv + l15) * AP + d0]);
      #pragma unroll
      for (int j = 0; j < 4; ++j) {
        bf16x8 bf = ldfrag(&Pc[(16 * j + l15) * AP + d0]);
        acch[j] = __builtin_amdgcn_mfma_f32_16x16x32_bf16(af, bf, acch[j], 0, 0, 0);
      }
    }
    #pragma unroll
    for (int j = 0; j < 4; ++j) {
      const int k = 16 * j + l15;
      const int nbase = 64 + 16 * wv + 4 * q;
      u32 w0 = (u32)f2bf(acch[j][0]) | ((u32)f2bf(acch[j][1]) << 16);
      u32 w1 = (u32)f2bf(acch[j][2]) | ((u32)f2bf(acch[j][3]) << 16);
      *reinterpret_cast<uint2*>(&Z1T[k * AP + nbase]) = make_uint2(w0, w1);
    }
  }
  __syncthreads();   // Z1T complete; adjb free

  // stage xfT into adjb tail
  unsigned short* xfT = adjb + 48 * AP;
  for (int i = tid; i < 2048; i += 256) {
    int n = i & 127, f = i >> 7;
    xfT[f * AP + n] = f2bf(x[((size_t)b * NN + n) * IND + 2 + f]);
  }
  __syncthreads();

  // M2: al2 = Pc @ Z1 ; M3: feats = Pc @ xf
  f32x4 acc2[4];
  f32x4 acc3 = f32x4{0.f, 0.f, 0.f, 0.f};
  #pragma unroll
  for (int j = 0; j < 4; ++j) acc2[j] = f32x4{0.f, 0.f, 0.f, 0.f};
  #pragma unroll
  for (int nt = 0; nt < 4; ++nt) {
    const int n0 = 32 * nt + 8 * q;
    bf16x8 af = ldfrag(&Pc[(16 * wv + l15) * AP + n0]);
    #pragma unroll
    for (int j = 0; j < 4; ++j) {
      bf16x8 bv = ldfrag(&Z1T[(16 * j + l15) * AP + n0]);
      acc2[j] = __builtin_amdgcn_mfma_f32_16x16x32_bf16(af, bv, acc2[j], 0, 0, 0);
    }
    bf16x8 bx = ldfrag(&xfT[l15 * AP + n0]);
    acc3 = __builtin_amdgcn_mfma_f32_16x16x32_bf16(af, bx, acc3, 0, 0, 0);
  }

  // LN reductions
  {
    float s1 = 0.f, q1 = 0.f, s2 = 0.f, q2 = 0.f;
    #pragma unroll
    for (int j = 0; j < 4; ++j)
      #pragma unroll
      for (int r = 0; r < 4; ++r) { float v = acc2[j][r]; s1 += v; q1 += v * v; }
    #pragma unroll
    for (int r = 0; r < 4; ++r) { float v = acc3[r]; s2 += v; q2 += v * v; }
    #pragma unroll
    for (int off = 1; off < 64; off <<= 1) {
      s1 += __shfl_xor(s1, off); q1 += __shfl_xor(q1, off);
      s2 += __shfl_xor(s2, off); q2 += __shfl_xor(q2, off);
    }
    if (lane == 0) { red[wv] = s1; red[4 + wv] = q1; red[8 + wv] = s2; red[12 + wv] = q2; }
  }
  __syncthreads();
  const float S1 = red[0] + red[1] + red[2] + red[3];
  const float Q1 = red[4] + red[5] + red[6] + red[7];
  const float S2 = red[8] + red[9] + red[10] + red[11];
  const float Q2 = red[12] + red[13] + red[14] + red[15];
  const float mean1 = S1 * (1.0f / 4096.0f);
  const float rstd1 = rsqrtf(Q1 * (1.0f / 4096.0f) - mean1 * mean1 + 1e-5f);
  const float mean2 = S2 * (1.0f / 1024.0f);
  const float rstd2 = rsqrtf(Q2 * (1.0f / 1024.0f) - mean2 * mean2 + 1e-5f);

  // normalize + bounce through freed LDS
  unsigned short* ob1 = adjb;
  unsigned short* ob2 = Z1T;
  #pragma unroll
  for (int j = 0; j < 4; ++j) {
    const int k = 16 * j + l15;
    #pragma unroll
    for (int r = 0; r < 4; ++r) {
      const int m = 16 * wv + 4 * q + r;
      const int pos = m * 64 + k;
      float vv2 = (acc2[j][r] - mean1) * rstd1 * ln1g[pos] + ln1b[pos];
      ob1[pos] = f2bf(vv2);
    }
  }
  {
    const int f = l15;
    #pragma unroll
    for (int r = 0; r < 4; ++r) {
      const int m = 16 * wv + 4 * q + r;
      const int pos = m * 16 + f;
      float vv2 = (acc3[r] - mean2) * rstd2 * ln2g[pos] + ln2b[pos];
      ob2[pos] = f2bf(vv2);
    }
  }
  __syncthreads();
  {
    const uint4* sp = reinterpret_cast<const uint4*>(ob1);
    uint4* dp = reinterpret_cast<uint4*>(lnadj + (size_t)b * 4096);
    for (int i = tid; i < 512; i += 256) dp[i] = sp[i];
    if (tid < 128)
      reinterpret_cast<uint4*>(lnfeats + (size_t)b * 1024)[tid] =
          reinterpret_cast<const uint4*>(ob2)[tid];
  }
}

// ---------------------------------------------------------------------------
// TAIL kernel (R16): fc4-GEMM + fc5-GEMM + fc6^T transpose in ONE dispatch.
// grid (32, 9), block 256: y<4 -> fc4 tile (n0=64y, K=4096, coff=0);
// y in 4..7 -> fc5 tile (n0=64(y-4), K=1024, coff=256); y==8 -> transpose.
// GEMM body = proven gemm_mfma_kernel (R5-R15).
// ---------------------------------------------------------------------------
#define GP 72
__launch_bounds__(256, 2)
__global__ void tail_kernel(const unsigned short* __restrict__ lnadj,
                            const float* __restrict__ fc4w, const float* __restrict__ fc4b,
                            const unsigned short* __restrict__ lnfeats,
                            const float* __restrict__ fc5w, const float* __restrict__ fc5b,
                            const float* __restrict__ fc6w,
                            float* __restrict__ h45,
                            float* __restrict__ wT6)
{
  const int tid = threadIdx.x;
  const int by = blockIdx.y;

  if (by == 8) {
    // transpose fc6w [64][512] -> wT6 [512][64]
    int idx = blockIdx.x * 256 + tid;
    for (; idx < 64 * 512; idx += 32 * 256) {
      int rr = idx >> 9, cc = idx & 511;
      wT6[cc * 64 + rr] = fc6w[idx];
    }
    return;
  }

  __shared__ __align__(16) unsigned short At[64 * GP];
  __shared__ __align__(16) unsigned short Wt[64 * GP];
  const bool is4 = (by < 4);
  const unsigned short* A = is4 ? lnadj : lnfeats;
  const float* W = is4 ? fc4w : fc5w;
  const float* bias = is4 ? fc4b : fc5b;
  const int K = is4 ? 4096 : 1024;
  const int coff = is4 ? 0 : 256;
  const int m0 = blockIdx.x * 64;
  const int n0 = (is4 ? by : (by - 4)) * 64;
  const int w = tid >> 6, lane = tid & 63;
  const int l15 = lane & 15, q = lane >> 4;
  const int srow = tid >> 2, sko = (tid & 3) * 16;

  f32x4 acc[4];
  #pragma unroll
  for (int j = 0; j < 4; ++j) acc[j] = f32x4{0.f, 0.f, 0.f, 0.f};

  for (int kc = 0; kc < K; kc += 64) {
    __syncthreads();
    {
      const unsigned short* ap = &A[(size_t)(m0 + srow) * K + kc + sko];
      *reinterpret_cast<uint4*>(&At[srow * GP + sko]) =
          *reinterpret_cast<const uint4*>(ap);
      *reinterpret_cast<uint4*>(&At[srow * GP + sko + 8]) =
          *reinterpret_cast<const uint4*>(ap + 8);
      const float* wp = &W[(size_t)(n0 + srow) * K + kc + sko];
      const float4 v0 = reinterpret_cast<const float4*>(wp)[0];
      const float4 v1 = reinterpret_cast<const float4*>(wp)[1];
      const float4 v2 = reinterpret_cast<const float4*>(wp)[2];
      const float4 v3 = reinterpret_cast<const float4*>(wp)[3];
      uint4 o0, o1;
      o0.x = (u32)f2bf(v0.x) | ((u32)f2bf(v0.y) << 16);
      o0.y = (u32)f2bf(v0.z) | ((u32)f2bf(v0.w) << 16);
      o0.z = (u32)f2bf(v1.x) | ((u32)f2bf(v1.y) << 16);
      o0.w = (u32)f2bf(v1.z) | ((u32)f2bf(v1.w) << 16);
      o1.x = (u32)f2bf(v2.x) | ((u32)f2bf(v2.y) << 16);
      o1.y = (u32)f2bf(v2.z) | ((u32)f2bf(v2.w) << 16);
      o1.z = (u32)f2bf(v3.x) | ((u32)f2bf(v3.y) << 16);
      o1.w = (u32)f2bf(v3.z) | ((u32)f2bf(v3.w) << 16);
      *reinterpret_cast<uint4*>(&Wt[srow * GP + sko]) = o0;
      *reinterpret_cast<uint4*>(&Wt[srow * GP + sko + 8]) = o1;
    }
    __syncthreads();
    #pragma unroll
    for (int s = 0; s < 2; ++s) {
      bf16x8 af = ldfrag(&At[(16 * w + l15) * GP + 32 * s + 8 * q]);
      #pragma unroll
      for (int j = 0; j < 4; ++j) {
        bf16x8 bf = ldfrag(&Wt[(16 * j + l15) * GP + 32 * s + 8 * q]);
        acc[j] = __builtin_amdgcn_mfma_f32_16x16x32_bf16(af, bf, acc[j], 0, 0, 0);
      }
    }
  }
  #pragma unroll
  for (int j = 0; j < 4; ++j) {
    const int col = n0 + 16 * j + l15;
    const float bb = bias[col];
    #pragma unroll
    for (int r = 0; r < 4; ++r) {
      const int m = m0 + 16 * w + 4 * q + r;
      h45[(size_t)m * 512 + coff + col] = fmaxf(acc[j][r] + bb, 0.0f);
    }
  }
}

// ---------------------------------------------------------------------------
// Kernel D: unchanged (8 rows/block).
// ---------------------------------------------------------------------------
__launch_bounds__(256)
__global__ void head_kernel(const float* __restrict__ h45,
                            const float* __restrict__ wT6,   // [512][64]
                            const float* __restrict__ b6,
                            const float* __restrict__ w7,    // [10][64]
                            const float* __restrict__ b7,
                            float* __restrict__ out)
{
  __shared__ float row[8][512];
  __shared__ float h6[8][64];
  __shared__ float zb[8][12];
  const int tid = threadIdx.x;
  const int r0 = blockIdx.x * 8;
  for (int i = tid; i < 8 * 128; i += 256) {
    int r = i >> 7, c4 = i & 127;
    *reinterpret_cast<float4*>(&row[r][c4 * 4]) =
        reinterpret_cast<const float4*>(h45 + (size_t)(r0 + r) * 512)[c4];
  }
  __syncthreads();
  const int o = tid & 63, rg = tid >> 6;
  float a0 = b6[o], a1 = a0;
  #pragma unroll 8
  for (int k = 0; k < 512; ++k) {
    float wv = wT6[k * 64 + o];
    a0 += row[rg][k] * wv;
    a1 += row[rg + 4][k] * wv;
  }
  h6[rg][o] = fmaxf(a0, 0.0f);
  h6[rg + 4][o] = fmaxf(a1, 0.0f);
  __syncthreads();
  if (tid < 80) {
    int r = tid / 10, c = tid - r * 10;
    float z = b7[c];
    #pragma unroll
    for (int k = 0; k < 64; ++k) z += h6[r][k] * w7[c * 64 + k];
    zb[r][c] = z;
  }
  __syncthreads();
  if (tid < 80) {
    int r = tid / 10, c = tid - r * 10;
    float mx = zb[r][0];
    #pragma unroll
    for (int j = 1; j < 10; ++j) mx = fmaxf(mx, zb[r][j]);
    float se = 0.f;
    #pragma unroll
    for (int j = 0; j < 10; ++j) se += __expf(zb[r][j] - mx);
    out[(size_t)(r0 + r) * 10 + c] = zb[r][c] - mx - __logf(se);
  }
}

// ---------------------------------------------------------------------------
extern "C" void kernel_launch(void* const* d_in, const int* in_sizes, int n_in,
                              void* d_out, int out_size, void* d_ws, size_t ws_size,
                              hipStream_t stream)
{
  (void)in_sizes; (void)n_in; (void)out_size; (void)ws_size;
  const float* x    = (const float*)d_in[0];
  const float* adj  = (const float*)d_in[1];
  const float* w1   = (const float*)d_in[2];
  const float* w2   = (const float*)d_in[3];
  const float* alpha = (const float*)d_in[4];
  const float* bin_score = (const float*)d_in[5];
  const float* fc2w = (const float*)d_in[6];
  const float* fc2b = (const float*)d_in[7];
  const float* fc3w = (const float*)d_in[8];
  const float* fc3b = (const float*)d_in[9];
  const float* ln1g = (const float*)d_in[10];
  const float* ln1b = (const float*)d_in[11];
  const float* fc4w = (const float*)d_in[12];
  const float* fc4b = (const float*)d_in[13];
  const float* ln2g = (const float*)d_in[14];
  const float* ln2b = (const float*)d_in[15];
  const float* fc5w = (const float*)d_in[16];
  const float* fc5b = (const float*)d_in[17];
  const float* fc6w = (const float*)d_in[18];
  const float* fc6b = (const float*)d_in[19];
  const float* fc7w = (const float*)d_in[20];
  const float* fc7b = (const float*)d_in[21];
  float* out = (float*)d_out;

  char* ws = (char*)d_ws;
  size_t off = 0;
  unsigned short* lnadj = (unsigned short*)(ws + off);  off += (size_t)2048 * 4096 * 2;
  unsigned short* lnfeats = (unsigned short*)(ws + off); off += (size_t)2048 * 1024 * 2;
  float* h45 = (float*)(ws + off);                      off += (size_t)2048 * 512 * 4;
  float* wT6 = (float*)(ws + off);                      off += (size_t)512 * 64 * 4;

  hipLaunchKernelGGL(fused_kernel, dim3(2048), dim3(256), 0, stream,
                     x, adj, w1, w2, alpha, bin_score,
                     fc2w, fc2b, fc3w, fc3b,
                     ln1g, ln1b, ln2g, ln2b, lnadj, lnfeats);
  hipLaunchKernelGGL(tail_kernel, dim3(32, 9), dim3(256), 0, stream,
                     lnadj, fc4w, fc4b, lnfeats, fc5w, fc5b, fc6w, h45, wT6);
  hipLaunchKernelGGL(head_kernel, dim3(256), dim3(256), 0, stream,
                     h45, wT6, fc6b, fc7w, fc7b, out);
}